// Round 1
// baseline (8981.611 us; speedup 1.0000x reference)
//
#include <hip/hip_runtime.h>

#define DIMS 32
#define HEADS 6
#define DD 192
#define NEG 0.2f

static inline int ceil_div(int a, int b){ return (a + b - 1) / b; }

// ---------------------------------------------------------------------------
// Projection GEMM: xl = x@Wl^T + bl, xr = x@Wr^T + br
// block = 192 threads, 16 nodes per block. W chunks staged transposed in LDS
// (padded stride 193 -> conflict-free), x tile broadcast-read from LDS.
// ---------------------------------------------------------------------------
__global__ __launch_bounds__(192) void proj_kernel(
    const float* __restrict__ x,
    const float* __restrict__ Wl, const float* __restrict__ bl,
    const float* __restrict__ Wr, const float* __restrict__ br,
    float* __restrict__ xl, float* __restrict__ xr, int N)
{
    __shared__ float xs[16 * DD];        // 12 KB
    __shared__ float wls[32][193];       // ~24.7 KB
    __shared__ float wrs[32][193];       // ~24.7 KB
    const int t = threadIdx.x;           // 0..191
    const int node0 = blockIdx.x * 16;

    // load x tile: 16*192 floats = 768 float4, 4 per thread (coalesced)
    {
        const float4* xg = (const float4*)(x + (size_t)node0 * DD);
        float4* xsv = (float4*)xs;
        #pragma unroll
        for (int i = 0; i < 4; ++i) xsv[t + 192 * i] = xg[t + 192 * i];
    }

    float accl[16], accr[16];
    #pragma unroll
    for (int n = 0; n < 16; ++n) { accl[n] = 0.f; accr[n] = 0.f; }

    for (int k0 = 0; k0 < DD; k0 += 32) {
        __syncthreads();
        // stage W[j][k0..k0+31] transposed: wls[kk][j] = Wl[j][k0+kk]
        #pragma unroll
        for (int i = 0; i < 8; ++i) {
            int j   = i * 24 + (t >> 3);
            int kk4 = (t & 7) * 4;
            float4 v = *(const float4*)(Wl + (size_t)j * DD + k0 + kk4);
            wls[kk4 + 0][j] = v.x; wls[kk4 + 1][j] = v.y;
            wls[kk4 + 2][j] = v.z; wls[kk4 + 3][j] = v.w;
            float4 u = *(const float4*)(Wr + (size_t)j * DD + k0 + kk4);
            wrs[kk4 + 0][j] = u.x; wrs[kk4 + 1][j] = u.y;
            wrs[kk4 + 2][j] = u.z; wrs[kk4 + 3][j] = u.w;
        }
        __syncthreads();
        #pragma unroll
        for (int kk4 = 0; kk4 < 8; ++kk4) {
            float wl0 = wls[kk4*4+0][t], wl1 = wls[kk4*4+1][t];
            float wl2 = wls[kk4*4+2][t], wl3 = wls[kk4*4+3][t];
            float wr0 = wrs[kk4*4+0][t], wr1 = wrs[kk4*4+1][t];
            float wr2 = wrs[kk4*4+2][t], wr3 = wrs[kk4*4+3][t];
            #pragma unroll
            for (int n = 0; n < 16; ++n) {
                float4 xv = *(const float4*)&xs[n * DD + k0 + kk4 * 4];
                accl[n] = fmaf(xv.x, wl0, fmaf(xv.y, wl1, fmaf(xv.z, wl2, fmaf(xv.w, wl3, accl[n]))));
                accr[n] = fmaf(xv.x, wr0, fmaf(xv.y, wr1, fmaf(xv.z, wr2, fmaf(xv.w, wr3, accr[n]))));
            }
        }
    }

    float bj_l = bl[t], bj_r = br[t];
    #pragma unroll
    for (int n = 0; n < 16; ++n) {
        size_t o = (size_t)(node0 + n) * DD + t;
        xl[o] = accl[n] + bj_l;
        xr[o] = accr[n] + bj_r;
    }
}

// ---------------------------------------------------------------------------
// Fused edge pass: one thread per (edge, head).
//   score = sum_c leaky_relu(xl[src]+xr[dst]) * att[h]
//   ev = exp(score)           (no max subtraction: scores bounded ~|9|)
//   denom[dst,h] += ev
//   agg[dst,h,:] += ev * xl[src,h,:]   (normalization deferred to finalize)
// ---------------------------------------------------------------------------
__global__ __launch_bounds__(256) void edge_kernel(
    const float* __restrict__ xl, const float* __restrict__ xr,
    const float* __restrict__ att, const int* __restrict__ ei,
    float* __restrict__ denom, float* __restrict__ agg, int E, int N)
{
    __shared__ float att_s[HEADS * DIMS];
    if (threadIdx.x < HEADS * DIMS / 4)
        ((float4*)att_s)[threadIdx.x] = ((const float4*)att)[threadIdx.x];
    __syncthreads();

    int tid = blockIdx.x * 256 + threadIdx.x;
    int total = (E + N) * HEADS;
    if (tid >= total) return;

    int e = tid / 6;
    int h = tid - e * 6;
    int src, dst;
    if (e < E) { src = ei[e]; dst = ei[E + e]; }
    else       { src = e - E; dst = e - E; }

    const float4* pa = (const float4*)(xl + (size_t)src * DD + h * DIMS);
    const float4* pb = (const float4*)(xr + (size_t)dst * DD + h * DIMS);
    const float4* pw = (const float4*)(att_s + h * DIMS);

    float4 a[8];
    float s = 0.f;
    #pragma unroll
    for (int i = 0; i < 8; ++i) {
        a[i] = pa[i];
        float4 b = pb[i];
        float4 w = pw[i];
        float m0 = a[i].x + b.x, m1 = a[i].y + b.y;
        float m2 = a[i].z + b.z, m3 = a[i].w + b.w;
        m0 = m0 > 0.f ? m0 : NEG * m0;
        m1 = m1 > 0.f ? m1 : NEG * m1;
        m2 = m2 > 0.f ? m2 : NEG * m2;
        m3 = m3 > 0.f ? m3 : NEG * m3;
        s = fmaf(m0, w.x, fmaf(m1, w.y, fmaf(m2, w.z, fmaf(m3, w.w, s))));
    }
    float ev = __expf(s);

    unsafeAtomicAdd(&denom[(size_t)dst * HEADS + h], ev);

    float* po = agg + (size_t)dst * DD + h * DIMS;
    #pragma unroll
    for (int i = 0; i < 8; ++i) {
        unsafeAtomicAdd(po + i * 4 + 0, ev * a[i].x);
        unsafeAtomicAdd(po + i * 4 + 1, ev * a[i].y);
        unsafeAtomicAdd(po + i * 4 + 2, ev * a[i].z);
        unsafeAtomicAdd(po + i * 4 + 3, ev * a[i].w);
    }
}

// ---------------------------------------------------------------------------
// Finalize: out = relu(x + agg/denom + bias)   (in-place on d_out == agg)
// ---------------------------------------------------------------------------
__global__ __launch_bounds__(256) void final_kernel(
    const float* __restrict__ x, const float* __restrict__ bias,
    const float* __restrict__ denom, float* __restrict__ out, int N)
{
    int i4 = blockIdx.x * 256 + threadIdx.x;
    int tot = N * (DD / 4);
    if (i4 >= tot) return;
    int n = i4 / 48;
    int r = i4 - n * 48;      // float4 index within row, 0..47
    int h = r >> 3;           // 8 float4 per head
    float inv = 1.f / (denom[n * HEADS + h] + 1e-16f);
    float4 a  = ((const float4*)out)[i4];
    float4 xv = ((const float4*)x)[i4];
    float4 b  = ((const float4*)bias)[r];
    float4 o;
    o.x = xv.x + a.x * inv + b.x; o.x = o.x > 0.f ? o.x : 0.f;
    o.y = xv.y + a.y * inv + b.y; o.y = o.y > 0.f ? o.y : 0.f;
    o.z = xv.z + a.z * inv + b.z; o.z = o.z > 0.f ? o.z : 0.f;
    o.w = xv.w + a.w * inv + b.w; o.w = o.w > 0.f ? o.w : 0.f;
    ((float4*)out)[i4] = o;
}

extern "C" void kernel_launch(void* const* d_in, const int* in_sizes, int n_in,
                              void* d_out, int out_size, void* d_ws, size_t ws_size,
                              hipStream_t stream)
{
    const float* x    = (const float*)d_in[0];
    const float* Wl   = (const float*)d_in[1];
    const float* bl   = (const float*)d_in[2];
    const float* Wr   = (const float*)d_in[3];
    const float* br   = (const float*)d_in[4];
    const float* att  = (const float*)d_in[5];
    const float* bias = (const float*)d_in[6];
    const int*   ei   = (const int*)d_in[7];

    const int N = in_sizes[0] / DD;     // 50000
    const int E = in_sizes[7] / 2;      // 800000

    float* out = (float*)d_out;
    char*  ws  = (char*)d_ws;
    size_t NB  = (size_t)N * DD * sizeof(float);
    float* xl    = (float*)(ws);
    float* xr    = (float*)(ws + NB);
    float* denom = (float*)(ws + 2 * NB);

    hipMemsetAsync(denom, 0, (size_t)N * HEADS * sizeof(float), stream);
    hipMemsetAsync(d_out, 0, (size_t)out_size * sizeof(float), stream);

    proj_kernel<<<N / 16, 192, 0, stream>>>(x, Wl, bl, Wr, br, xl, xr, N);

    int total = (E + N) * HEADS;
    edge_kernel<<<ceil_div(total, 256), 256, 0, stream>>>(xl, xr, att, ei, denom, out, E, N);

    final_kernel<<<ceil_div(N * (DD / 4), 256), 256, 0, stream>>>(x, bias, denom, out, N);
}

// Round 2
// 678.978 us; speedup vs baseline: 13.2281x; 13.2281x over previous
//
#include <hip/hip_runtime.h>

#define DIMS 32
#define HEADS 6
#define DD 192
#define NEG 0.2f

static inline int ceil_div(int a, int b){ return (a + b - 1) / b; }

// ---------------------------------------------------------------------------
// Projection GEMM: xl = x@Wl^T + bl, xr = x@Wr^T + br   (xr lands in d_out)
// ---------------------------------------------------------------------------
__global__ __launch_bounds__(192) void proj_kernel(
    const float* __restrict__ x,
    const float* __restrict__ Wl, const float* __restrict__ bl,
    const float* __restrict__ Wr, const float* __restrict__ br,
    float* __restrict__ xl, float* __restrict__ xr, int N)
{
    __shared__ float xs[16 * DD];
    __shared__ float wls[32][193];
    __shared__ float wrs[32][193];
    const int t = threadIdx.x;
    const int node0 = blockIdx.x * 16;

    {
        const float4* xg = (const float4*)(x + (size_t)node0 * DD);
        float4* xsv = (float4*)xs;
        #pragma unroll
        for (int i = 0; i < 4; ++i) xsv[t + 192 * i] = xg[t + 192 * i];
    }

    float accl[16], accr[16];
    #pragma unroll
    for (int n = 0; n < 16; ++n) { accl[n] = 0.f; accr[n] = 0.f; }

    for (int k0 = 0; k0 < DD; k0 += 32) {
        __syncthreads();
        #pragma unroll
        for (int i = 0; i < 8; ++i) {
            int j   = i * 24 + (t >> 3);
            int kk4 = (t & 7) * 4;
            float4 v = *(const float4*)(Wl + (size_t)j * DD + k0 + kk4);
            wls[kk4 + 0][j] = v.x; wls[kk4 + 1][j] = v.y;
            wls[kk4 + 2][j] = v.z; wls[kk4 + 3][j] = v.w;
            float4 u = *(const float4*)(Wr + (size_t)j * DD + k0 + kk4);
            wrs[kk4 + 0][j] = u.x; wrs[kk4 + 1][j] = u.y;
            wrs[kk4 + 2][j] = u.z; wrs[kk4 + 3][j] = u.w;
        }
        __syncthreads();
        #pragma unroll
        for (int kk4 = 0; kk4 < 8; ++kk4) {
            float wl0 = wls[kk4*4+0][t], wl1 = wls[kk4*4+1][t];
            float wl2 = wls[kk4*4+2][t], wl3 = wls[kk4*4+3][t];
            float wr0 = wrs[kk4*4+0][t], wr1 = wrs[kk4*4+1][t];
            float wr2 = wrs[kk4*4+2][t], wr3 = wrs[kk4*4+3][t];
            #pragma unroll
            for (int n = 0; n < 16; ++n) {
                float4 xv = *(const float4*)&xs[n * DD + k0 + kk4 * 4];
                accl[n] = fmaf(xv.x, wl0, fmaf(xv.y, wl1, fmaf(xv.z, wl2, fmaf(xv.w, wl3, accl[n]))));
                accr[n] = fmaf(xv.x, wr0, fmaf(xv.y, wr1, fmaf(xv.z, wr2, fmaf(xv.w, wr3, accr[n]))));
            }
        }
    }

    float bj_l = bl[t], bj_r = br[t];
    #pragma unroll
    for (int n = 0; n < 16; ++n) {
        size_t o = (size_t)(node0 + n) * DD + t;
        xl[o] = accl[n] + bj_l;
        xr[o] = accr[n] + bj_r;
    }
}

// ---------------------------------------------------------------------------
// CSR build: degree histogram -> single-block scan -> bucket scatter
// ---------------------------------------------------------------------------
__global__ __launch_bounds__(256) void deg_kernel(
    const int* __restrict__ ei, int* __restrict__ deg, int E)
{
    int e = blockIdx.x * 256 + threadIdx.x;
    if (e < E) atomicAdd(&deg[ei[E + e]], 1);
}

__global__ __launch_bounds__(1024) void scan_kernel(
    const int* __restrict__ deg, int* __restrict__ rowptr, int N)
{
    __shared__ int sums[1024];
    const int t = threadIdx.x;
    const int chunk = (N + 1023) / 1024;
    int lo = t * chunk; if (lo > N) lo = N;
    int hi = lo + chunk; if (hi > N) hi = N;
    int s = 0;
    for (int i = lo; i < hi; ++i) s += deg[i];
    sums[t] = s;
    __syncthreads();
    for (int off = 1; off < 1024; off <<= 1) {
        int tmp = (t >= off) ? sums[t - off] : 0;
        __syncthreads();
        sums[t] += tmp;
        __syncthreads();
    }
    int run = sums[t] - s;              // exclusive prefix of this chunk
    for (int i = lo; i < hi; ++i) { rowptr[i] = run; run += deg[i]; }
    if (t == 1023) rowptr[N] = sums[1023];
}

__global__ __launch_bounds__(256) void scatter_kernel(
    const int* __restrict__ ei, const int* __restrict__ rowptr,
    int* __restrict__ cur, int* __restrict__ col, int E)
{
    int e = blockIdx.x * 256 + threadIdx.x;
    if (e >= E) return;
    int src = ei[e], dst = ei[E + e];
    int pos = atomicAdd(&cur[dst], 1);
    col[rowptr[dst] + pos] = src;
}

// ---------------------------------------------------------------------------
// Pull aggregation: one wave per dst node, lane l owns dims {l, l+64, l+128}.
// Per edge: gather xl[src], score via leaky_relu+att dot, 32-lane butterfly
// reduce per head, exp, accumulate numerator+denominator in registers.
// Tail fuses residual + bias + ReLU. xr lives in `out` and is overwritten.
// ---------------------------------------------------------------------------
__global__ __launch_bounds__(256) void agg_kernel(
    const float* __restrict__ xl, const float* __restrict__ att,
    const float* __restrict__ x, const float* __restrict__ bias,
    const int* __restrict__ rowptr, const int* __restrict__ col,
    float* __restrict__ out, int N)
{
    const int node = blockIdx.x * 4 + (threadIdx.x >> 6);
    if (node >= N) return;
    const int lane = threadIdx.x & 63;
    const size_t base = (size_t)node * DD + lane;

    const float xr0 = out[base], xr1 = out[base + 64], xr2 = out[base + 128];
    const float w0 = att[lane], w1 = att[lane + 64], w2 = att[lane + 128];

    float acc0 = 0.f, acc1 = 0.f, acc2 = 0.f;
    float den0 = 0.f, den1 = 0.f, den2 = 0.f;

    auto process = [&](int src) {
        size_t sb = (size_t)src * DD + lane;
        float a0 = xl[sb], a1 = xl[sb + 64], a2 = xl[sb + 128];
        float m0 = a0 + xr0, m1 = a1 + xr1, m2 = a2 + xr2;
        m0 = m0 > 0.f ? m0 : NEG * m0;
        m1 = m1 > 0.f ? m1 : NEG * m1;
        m2 = m2 > 0.f ? m2 : NEG * m2;
        float p0 = m0 * w0, p1 = m1 * w1, p2 = m2 * w2;
        #pragma unroll
        for (int msk = 1; msk < 32; msk <<= 1) {
            p0 += __shfl_xor(p0, msk, 64);
            p1 += __shfl_xor(p1, msk, 64);
            p2 += __shfl_xor(p2, msk, 64);
        }
        float e0 = __expf(p0), e1 = __expf(p1), e2 = __expf(p2);
        den0 += e0; den1 += e1; den2 += e2;
        acc0 = fmaf(e0, a0, acc0);
        acc1 = fmaf(e1, a1, acc1);
        acc2 = fmaf(e2, a2, acc2);
    };

    process(node);                       // self-loop
    const int kbeg = rowptr[node], kend = rowptr[node + 1];
    for (int k = kbeg; k < kend; ++k) process(col[k]);

    float o0 = x[base]       + acc0 / (den0 + 1e-16f) + bias[lane];
    float o1 = x[base + 64]  + acc1 / (den1 + 1e-16f) + bias[lane + 64];
    float o2 = x[base + 128] + acc2 / (den2 + 1e-16f) + bias[lane + 128];
    out[base]       = o0 > 0.f ? o0 : 0.f;
    out[base + 64]  = o1 > 0.f ? o1 : 0.f;
    out[base + 128] = o2 > 0.f ? o2 : 0.f;
}

extern "C" void kernel_launch(void* const* d_in, const int* in_sizes, int n_in,
                              void* d_out, int out_size, void* d_ws, size_t ws_size,
                              hipStream_t stream)
{
    const float* x    = (const float*)d_in[0];
    const float* Wl   = (const float*)d_in[1];
    const float* bl   = (const float*)d_in[2];
    const float* Wr   = (const float*)d_in[3];
    const float* br   = (const float*)d_in[4];
    const float* att  = (const float*)d_in[5];
    const float* bias = (const float*)d_in[6];
    const int*   ei   = (const int*)d_in[7];

    const int N = in_sizes[0] / DD;     // 50000
    const int E = in_sizes[7] / 2;      // 800000

    float* out = (float*)d_out;
    char*  ws  = (char*)d_ws;
    size_t NB  = (size_t)N * DD * sizeof(float);

    float* xl     = (float*)(ws);                       // 38.4 MB
    int*   rowptr = (int*)(ws + NB);                    // (N+1)*4
    int*   deg    = (int*)(ws + NB + (size_t)(N+1)*4);  // N*4
    int*   cur    = (int*)(ws + NB + (size_t)(2*N+1)*4);// N*4
    int*   col    = (int*)(ws + NB + (size_t)(3*N+1)*4);// E*4

    hipMemsetAsync(deg, 0, (size_t)N * sizeof(int), stream);
    hipMemsetAsync(cur, 0, (size_t)N * sizeof(int), stream);

    proj_kernel<<<N / 16, 192, 0, stream>>>(x, Wl, bl, Wr, br, xl, out, N);
    deg_kernel<<<ceil_div(E, 256), 256, 0, stream>>>(ei, deg, E);
    scan_kernel<<<1, 1024, 0, stream>>>(deg, rowptr, N);
    scatter_kernel<<<ceil_div(E, 256), 256, 0, stream>>>(ei, rowptr, cur, col, E);
    agg_kernel<<<ceil_div(N, 4), 256, 0, stream>>>(xl, att, x, bias, rowptr, col, out, N);
}

// Round 3
// 461.183 us; speedup vs baseline: 19.4752x; 1.4723x over previous
//
#include <hip/hip_runtime.h>

#define DIMS 32
#define HEADS 6
#define DD 192
#define NEG 0.2f

typedef float f32x4 __attribute__((ext_vector_type(4)));
typedef short bf16x8 __attribute__((ext_vector_type(8)));

static inline int ceil_div(int a, int b){ return (a + b - 1) / b; }

static __device__ __forceinline__ unsigned short f2bf(float f) {
    unsigned u = __float_as_uint(f);
    u += 0x7FFF + ((u >> 16) & 1);          // round-to-nearest-even
    return (unsigned short)(u >> 16);
}
static __device__ __forceinline__ float bf2f(unsigned short h) {
    return __uint_as_float((unsigned)h << 16);
}

// ---------------------------------------------------------------------------
// W pre-conversion: split Wl/Wr into hi/lo bf16 (192*192 each, L2-resident)
// ---------------------------------------------------------------------------
__global__ __launch_bounds__(256) void conv_w(
    const float* __restrict__ Wl, const float* __restrict__ Wr,
    short* __restrict__ wlh, short* __restrict__ wll,
    short* __restrict__ wrh, short* __restrict__ wrl)
{
    int i = blockIdx.x * 256 + threadIdx.x;
    if (i >= DD * DD) return;
    float f = Wl[i];
    unsigned short h = f2bf(f);
    wlh[i] = (short)h;
    wll[i] = (short)f2bf(f - bf2f(h));
    f = Wr[i];
    h = f2bf(f);
    wrh[i] = (short)h;
    wrl[i] = (short)f2bf(f - bf2f(h));
}

// ---------------------------------------------------------------------------
// Projection via MFMA (bf16x3 split precision, ~f32 accurate):
//   xl = x@Wl^T + bl   (ws),   xr = x@Wr^T + br   (d_out)
// One wave per 16 nodes. A-frags (x) converted hi/lo in-register, held for
// the whole kernel. W row-major [j][k] is the B^T layout MFMA wants: frag =
// 8 contiguous k as one short8. No LDS. 12 col-tiles x {L,R} per wave.
// ---------------------------------------------------------------------------
__global__ __launch_bounds__(256) void proj_mfma(
    const float* __restrict__ x,
    const short* __restrict__ wlh, const short* __restrict__ wll,
    const short* __restrict__ wrh, const short* __restrict__ wrl,
    const float* __restrict__ bl, const float* __restrict__ br,
    float* __restrict__ xl, float* __restrict__ xr, int N)
{
    const int wt = blockIdx.x * 4 + (threadIdx.x >> 6);
    const int n0 = wt * 16;
    if (n0 >= N) return;
    const int lane = threadIdx.x & 63;
    const int rr   = lane & 15;      // A-row / B-col / D-col
    const int kg   = lane >> 4;      // k-group 0..3

    // ---- load + split A fragments: x[n0+rr][kg*8 + 32s + e], s=0..5 ----
    bf16x8 ah[6], al[6];
    const float* xrow = x + (size_t)(n0 + rr) * DD + kg * 8;
    #pragma unroll
    for (int s = 0; s < 6; ++s) {
        f32x4 v0 = *(const f32x4*)(xrow + 32 * s);
        f32x4 v1 = *(const f32x4*)(xrow + 32 * s + 4);
        #pragma unroll
        for (int e = 0; e < 8; ++e) {
            float f = (e < 4) ? v0[e] : v1[e - 4];
            unsigned short h = f2bf(f);
            ah[s][e] = (short)h;
            al[s][e] = (short)f2bf(f - bf2f(h));
        }
    }

    // ---- 12 col-tiles; per tile two independent acc chains (Wl, Wr) ----
    #pragma unroll 1
    for (int j = 0; j < 12; ++j) {
        f32x4 aL = {0.f, 0.f, 0.f, 0.f};
        f32x4 aR = {0.f, 0.f, 0.f, 0.f};
        const size_t base = (size_t)(16 * j + rr) * DD + kg * 8;
        #pragma unroll
        for (int s = 0; s < 6; ++s) {
            bf16x8 bLh = *(const bf16x8*)(wlh + base + 32 * s);
            bf16x8 bLl = *(const bf16x8*)(wll + base + 32 * s);
            bf16x8 bRh = *(const bf16x8*)(wrh + base + 32 * s);
            bf16x8 bRl = *(const bf16x8*)(wrl + base + 32 * s);
            aL = __builtin_amdgcn_mfma_f32_16x16x32_bf16(ah[s], bLh, aL, 0, 0, 0);
            aR = __builtin_amdgcn_mfma_f32_16x16x32_bf16(ah[s], bRh, aR, 0, 0, 0);
            aL = __builtin_amdgcn_mfma_f32_16x16x32_bf16(al[s], bLh, aL, 0, 0, 0);
            aR = __builtin_amdgcn_mfma_f32_16x16x32_bf16(al[s], bRh, aR, 0, 0, 0);
            aL = __builtin_amdgcn_mfma_f32_16x16x32_bf16(ah[s], bLl, aL, 0, 0, 0);
            aR = __builtin_amdgcn_mfma_f32_16x16x32_bf16(ah[s], bRl, aR, 0, 0, 0);
        }
        // epilogue: D col = 16j+rr, D row = n0 + kg*4 + r
        const int col = 16 * j + rr;
        const float bcl = bl[col], bcr = br[col];
        #pragma unroll
        for (int r = 0; r < 4; ++r) {
            size_t o = (size_t)(n0 + kg * 4 + r) * DD + col;
            xl[o] = aL[r] + bcl;
            xr[o] = aR[r] + bcr;
        }
    }
}

// ---------------------------------------------------------------------------
// CSR build: degree histogram -> single-block scan -> bucket scatter
// ---------------------------------------------------------------------------
__global__ __launch_bounds__(256) void deg_kernel(
    const int* __restrict__ ei, int* __restrict__ deg, int E)
{
    int e = blockIdx.x * 256 + threadIdx.x;
    if (e < E) atomicAdd(&deg[ei[E + e]], 1);
}

__global__ __launch_bounds__(1024) void scan_kernel(
    const int* __restrict__ deg, int* __restrict__ rowptr, int N)
{
    __shared__ int sums[1024];
    const int t = threadIdx.x;
    const int chunk = (N + 1023) / 1024;
    int lo = t * chunk; if (lo > N) lo = N;
    int hi = lo + chunk; if (hi > N) hi = N;
    int s = 0;
    for (int i = lo; i < hi; ++i) s += deg[i];
    sums[t] = s;
    __syncthreads();
    for (int off = 1; off < 1024; off <<= 1) {
        int tmp = (t >= off) ? sums[t - off] : 0;
        __syncthreads();
        sums[t] += tmp;
        __syncthreads();
    }
    int run = sums[t] - s;
    for (int i = lo; i < hi; ++i) { rowptr[i] = run; run += deg[i]; }
    if (t == 1023) rowptr[N] = sums[1023];
}

__global__ __launch_bounds__(256) void scatter_kernel(
    const int* __restrict__ ei, const int* __restrict__ rowptr,
    int* __restrict__ cur, int* __restrict__ col, int E)
{
    int e = blockIdx.x * 256 + threadIdx.x;
    if (e >= E) return;
    int src = ei[e], dst = ei[E + e];
    int pos = atomicAdd(&cur[dst], 1);
    col[rowptr[dst] + pos] = src;
}

// ---------------------------------------------------------------------------
// Pull aggregation: one wave per dst node, lane l owns dims {l, l+64, l+128}.
// ---------------------------------------------------------------------------
__global__ __launch_bounds__(256) void agg_kernel(
    const float* __restrict__ xl, const float* __restrict__ att,
    const float* __restrict__ x, const float* __restrict__ bias,
    const int* __restrict__ rowptr, const int* __restrict__ col,
    float* __restrict__ out, int N)
{
    const int node = blockIdx.x * 4 + (threadIdx.x >> 6);
    if (node >= N) return;
    const int lane = threadIdx.x & 63;
    const size_t base = (size_t)node * DD + lane;

    const float xr0 = out[base], xr1 = out[base + 64], xr2 = out[base + 128];
    const float w0 = att[lane], w1 = att[lane + 64], w2 = att[lane + 128];

    float acc0 = 0.f, acc1 = 0.f, acc2 = 0.f;
    float den0 = 0.f, den1 = 0.f, den2 = 0.f;

    auto process = [&](int src) {
        size_t sb = (size_t)src * DD + lane;
        float a0 = xl[sb], a1 = xl[sb + 64], a2 = xl[sb + 128];
        float m0 = a0 + xr0, m1 = a1 + xr1, m2 = a2 + xr2;
        m0 = m0 > 0.f ? m0 : NEG * m0;
        m1 = m1 > 0.f ? m1 : NEG * m1;
        m2 = m2 > 0.f ? m2 : NEG * m2;
        float p0 = m0 * w0, p1 = m1 * w1, p2 = m2 * w2;
        #pragma unroll
        for (int msk = 1; msk < 32; msk <<= 1) {
            p0 += __shfl_xor(p0, msk, 64);
            p1 += __shfl_xor(p1, msk, 64);
            p2 += __shfl_xor(p2, msk, 64);
        }
        float e0 = __expf(p0), e1 = __expf(p1), e2 = __expf(p2);
        den0 += e0; den1 += e1; den2 += e2;
        acc0 = fmaf(e0, a0, acc0);
        acc1 = fmaf(e1, a1, acc1);
        acc2 = fmaf(e2, a2, acc2);
    };

    process(node);                       // self-loop
    const int kbeg = rowptr[node], kend = rowptr[node + 1];
    for (int k = kbeg; k < kend; ++k) process(col[k]);

    float o0 = x[base]       + acc0 / (den0 + 1e-16f) + bias[lane];
    float o1 = x[base + 64]  + acc1 / (den1 + 1e-16f) + bias[lane + 64];
    float o2 = x[base + 128] + acc2 / (den2 + 1e-16f) + bias[lane + 128];
    out[base]       = o0 > 0.f ? o0 : 0.f;
    out[base + 64]  = o1 > 0.f ? o1 : 0.f;
    out[base + 128] = o2 > 0.f ? o2 : 0.f;
}

extern "C" void kernel_launch(void* const* d_in, const int* in_sizes, int n_in,
                              void* d_out, int out_size, void* d_ws, size_t ws_size,
                              hipStream_t stream)
{
    const float* x    = (const float*)d_in[0];
    const float* Wl   = (const float*)d_in[1];
    const float* bl   = (const float*)d_in[2];
    const float* Wr   = (const float*)d_in[3];
    const float* br   = (const float*)d_in[4];
    const float* att  = (const float*)d_in[5];
    const float* bias = (const float*)d_in[6];
    const int*   ei   = (const int*)d_in[7];

    const int N = in_sizes[0] / DD;     // 50000
    const int E = in_sizes[7] / 2;      // 800000

    float* out = (float*)d_out;
    char*  ws  = (char*)d_ws;
    size_t NB  = (size_t)N * DD * sizeof(float);      // 38.4 MB
    const size_t WSZ = (size_t)DD * DD * sizeof(short); // 73728 B

    float* xlbuf = (float*)(ws);
    short* wlh   = (short*)(ws + NB);
    short* wll   = (short*)(ws + NB + WSZ);
    short* wrh   = (short*)(ws + NB + 2 * WSZ);
    short* wrl   = (short*)(ws + NB + 3 * WSZ);
    char*  csr   = ws + NB + 4 * WSZ;
    int*   rowptr = (int*)(csr);
    int*   deg    = (int*)(csr + (size_t)(N + 1) * 4);
    int*   cur    = (int*)(csr + (size_t)(2 * N + 1) * 4);
    int*   col    = (int*)(csr + (size_t)(3 * N + 1) * 4);

    hipMemsetAsync(deg, 0, (size_t)N * sizeof(int), stream);
    hipMemsetAsync(cur, 0, (size_t)N * sizeof(int), stream);

    conv_w<<<ceil_div(DD * DD, 256), 256, 0, stream>>>(Wl, Wr, wlh, wll, wrh, wrl);
    proj_mfma<<<ceil_div(N, 64), 256, 0, stream>>>(x, wlh, wll, wrh, wrl, bl, br, xlbuf, out, N);
    deg_kernel<<<ceil_div(E, 256), 256, 0, stream>>>(ei, deg, E);
    scan_kernel<<<1, 1024, 0, stream>>>(deg, rowptr, N);
    scatter_kernel<<<ceil_div(E, 256), 256, 0, stream>>>(ei, rowptr, cur, col, E);
    agg_kernel<<<ceil_div(N, 4), 256, 0, stream>>>(xlbuf, att, x, bias, rowptr, col, out, N);
}

// Round 4
// 268.661 us; speedup vs baseline: 33.4310x; 1.7166x over previous
//
#include <hip/hip_runtime.h>

#define DD 192
#define NEG 0.2f

typedef float f32x4 __attribute__((ext_vector_type(4)));
typedef short bf16x8 __attribute__((ext_vector_type(8)));

static inline int ceil_div(int a, int b){ return (a + b - 1) / b; }
static inline size_t alignup(size_t x){ return (x + 511) & ~(size_t)511; }

static __device__ __forceinline__ unsigned short f2bf(float f) {
    unsigned u = __float_as_uint(f);
    u += 0x7FFF + ((u >> 16) & 1);          // round-to-nearest-even
    return (unsigned short)(u >> 16);
}
static __device__ __forceinline__ float bf2f(unsigned short h) {
    return __uint_as_float((unsigned)h << 16);
}

// DPP xor-add within 16-lane rows: masks {1,2,7,15} span the 16-group.
#define DPPA(p, ctrl) do { \
    int _t = __builtin_amdgcn_update_dpp(0, __float_as_int(p), ctrl, 0xf, 0xf, true); \
    (p) += __int_as_float(_t); } while (0)
#define RED16(p) do { DPPA(p,0xB1); DPPA(p,0x4E); DPPA(p,0x141); DPPA(p,0x140); } while (0)

// ---------------------------------------------------------------------------
// W pre-conversion: split Wl/Wr into hi/lo bf16
// ---------------------------------------------------------------------------
__global__ __launch_bounds__(256) void conv_w(
    const float* __restrict__ Wl, const float* __restrict__ Wr,
    short* __restrict__ wlh, short* __restrict__ wll,
    short* __restrict__ wrh, short* __restrict__ wrl)
{
    int i = blockIdx.x * 256 + threadIdx.x;
    if (i >= DD * DD) return;
    float f = Wl[i];
    unsigned short h = f2bf(f);
    wlh[i] = (short)h;
    wll[i] = (short)f2bf(f - bf2f(h));
    f = Wr[i];
    h = f2bf(f);
    wrh[i] = (short)h;
    wrl[i] = (short)f2bf(f - bf2f(h));
}

// ---------------------------------------------------------------------------
// Projection via MFMA (bf16x3 split): xl -> bf16 (ws), xr -> f32 (d_out)
// ---------------------------------------------------------------------------
__global__ __launch_bounds__(256) void proj_mfma(
    const float* __restrict__ x,
    const short* __restrict__ wlh, const short* __restrict__ wll,
    const short* __restrict__ wrh, const short* __restrict__ wrl,
    const float* __restrict__ bl, const float* __restrict__ br,
    unsigned short* __restrict__ xlb, float* __restrict__ xr, int N)
{
    const int wt = blockIdx.x * 4 + (threadIdx.x >> 6);
    const int n0 = wt * 16;
    if (n0 >= N) return;
    const int lane = threadIdx.x & 63;
    const int rr   = lane & 15;
    const int kg   = lane >> 4;

    bf16x8 ah[6], al[6];
    const float* xrow = x + (size_t)(n0 + rr) * DD + kg * 8;
    #pragma unroll
    for (int s = 0; s < 6; ++s) {
        f32x4 v0 = *(const f32x4*)(xrow + 32 * s);
        f32x4 v1 = *(const f32x4*)(xrow + 32 * s + 4);
        #pragma unroll
        for (int e = 0; e < 8; ++e) {
            float f = (e < 4) ? v0[e] : v1[e - 4];
            unsigned short h = f2bf(f);
            ah[s][e] = (short)h;
            al[s][e] = (short)f2bf(f - bf2f(h));
        }
    }

    #pragma unroll 1
    for (int j = 0; j < 12; ++j) {
        f32x4 aL = {0.f, 0.f, 0.f, 0.f};
        f32x4 aR = {0.f, 0.f, 0.f, 0.f};
        const size_t base = (size_t)(16 * j + rr) * DD + kg * 8;
        #pragma unroll
        for (int s = 0; s < 6; ++s) {
            bf16x8 bLh = *(const bf16x8*)(wlh + base + 32 * s);
            bf16x8 bLl = *(const bf16x8*)(wll + base + 32 * s);
            bf16x8 bRh = *(const bf16x8*)(wrh + base + 32 * s);
            bf16x8 bRl = *(const bf16x8*)(wrl + base + 32 * s);
            aL = __builtin_amdgcn_mfma_f32_16x16x32_bf16(ah[s], bLh, aL, 0, 0, 0);
            aR = __builtin_amdgcn_mfma_f32_16x16x32_bf16(ah[s], bRh, aR, 0, 0, 0);
            aL = __builtin_amdgcn_mfma_f32_16x16x32_bf16(al[s], bLh, aL, 0, 0, 0);
            aR = __builtin_amdgcn_mfma_f32_16x16x32_bf16(al[s], bRh, aR, 0, 0, 0);
            aL = __builtin_amdgcn_mfma_f32_16x16x32_bf16(ah[s], bLl, aL, 0, 0, 0);
            aR = __builtin_amdgcn_mfma_f32_16x16x32_bf16(ah[s], bRl, aR, 0, 0, 0);
        }
        const int col = 16 * j + rr;
        const float bcl = bl[col], bcr = br[col];
        #pragma unroll
        for (int r = 0; r < 4; ++r) {
            size_t o = (size_t)(n0 + kg * 4 + r) * DD + col;
            xlb[o] = f2bf(aL[r] + bcl);
            xr[o]  = aR[r] + bcr;
        }
    }
}

// ---------------------------------------------------------------------------
// CSR build: degree+pos -> 3-kernel parallel scan -> atomic-free scatter
// ---------------------------------------------------------------------------
__global__ __launch_bounds__(256) void deg_kernel(
    const int* __restrict__ ei, int* __restrict__ deg, int* __restrict__ pos, int E)
{
    int e = blockIdx.x * 256 + threadIdx.x;
    if (e < E) pos[e] = atomicAdd(&deg[ei[E + e]], 1);
}

__global__ __launch_bounds__(256) void scan1(
    const int* __restrict__ deg, int* __restrict__ bsum, int N)
{
    __shared__ int s[256];
    int t = threadIdx.x, i = blockIdx.x * 256 + t;
    s[t] = (i < N) ? deg[i] : 0;
    __syncthreads();
    for (int o = 128; o > 0; o >>= 1) {
        if (t < o) s[t] += s[t + o];
        __syncthreads();
    }
    if (t == 0) bsum[blockIdx.x] = s[0];
}

__global__ __launch_bounds__(256) void scan2(
    int* __restrict__ bsum, int* __restrict__ rowptr, int nb, int N)
{
    __shared__ int s[256];
    int t = threadIdx.x;
    int v = (t < nb) ? bsum[t] : 0;
    s[t] = v;
    __syncthreads();
    for (int o = 1; o < 256; o <<= 1) {
        int u = (t >= o) ? s[t - o] : 0;
        __syncthreads();
        s[t] += u;
        __syncthreads();
    }
    if (t < nb) bsum[t] = s[t] - v;       // exclusive block prefix
    if (t == 255) rowptr[N] = s[255];     // total = E
}

__global__ __launch_bounds__(256) void scan3(
    const int* __restrict__ deg, const int* __restrict__ bsum,
    int* __restrict__ rowptr, int N)
{
    __shared__ int s[256];
    int t = threadIdx.x, i = blockIdx.x * 256 + t;
    int v = (i < N) ? deg[i] : 0;
    s[t] = v;
    __syncthreads();
    for (int o = 1; o < 256; o <<= 1) {
        int u = (t >= o) ? s[t - o] : 0;
        __syncthreads();
        s[t] += u;
        __syncthreads();
    }
    if (i < N) rowptr[i] = bsum[blockIdx.x] + s[t] - v;
}

__global__ __launch_bounds__(256) void scatter_kernel(
    const int* __restrict__ ei, const int* __restrict__ rowptr,
    const int* __restrict__ pos, int* __restrict__ col, int E)
{
    int e = blockIdx.x * 256 + threadIdx.x;
    if (e >= E) return;
    col[rowptr[ei[E + e]] + pos[e]] = ei[e];
}

// ---------------------------------------------------------------------------
// Pull aggregation: one wave per dst node, TWO edges per iteration
// (lanes 0-31 edge A, 32-63 edge B). Lane owns dim-pairs {2l,2l+1},
// {64+2l,..}, {128+2l,..}; each head = one 16-lane group -> 4-step DPP reduce.
// Pipelined: col 2 ahead, xl row 1 ahead. Tail fuses residual+bias+ReLU.
// ---------------------------------------------------------------------------
__global__ __launch_bounds__(256) void agg_kernel(
    const unsigned short* __restrict__ xlb, const float* __restrict__ att,
    const float* __restrict__ x, const float* __restrict__ bias,
    const int* __restrict__ rowptr, const int* __restrict__ col,
    float* __restrict__ out, int N)
{
    const int node = blockIdx.x * 4 + (threadIdx.x >> 6);
    if (node >= N) return;
    const int lane = threadIdx.x & 63;
    const int l    = lane & 31;
    const int half = lane >> 5;
    const size_t base = (size_t)node * DD;

    const float2 xr0 = *(const float2*)(out + base + 2 * l);
    const float2 xr1 = *(const float2*)(out + base + 64 + 2 * l);
    const float2 xr2 = *(const float2*)(out + base + 128 + 2 * l);
    const float2 wv0 = *(const float2*)(att + 2 * l);
    const float2 wv1 = *(const float2*)(att + 64 + 2 * l);
    const float2 wv2 = *(const float2*)(att + 128 + 2 * l);
    // leaky_relu(m)*w = (0.6w)*m + (0.4w)*|m|
    const float w60x = 0.6f * wv0.x, w40x = 0.4f * wv0.x, w60y = 0.6f * wv0.y, w40y = 0.4f * wv0.y;
    const float w61x = 0.6f * wv1.x, w41x = 0.4f * wv1.x, w61y = 0.6f * wv1.y, w41y = 0.4f * wv1.y;
    const float w62x = 0.6f * wv2.x, w42x = 0.4f * wv2.x, w62y = 0.6f * wv2.y, w42y = 0.4f * wv2.y;

    float acc0x = 0.f, acc0y = 0.f, acc1x = 0.f, acc1y = 0.f, acc2x = 0.f, acc2y = 0.f;
    float den0 = 0.f, den1 = 0.f, den2 = 0.f;

    const int kbeg  = rowptr[node];
    const int total = rowptr[node + 1] - kbeg + 1;    // self + deg

    auto srcof = [&](int i) -> int {
        int slot = i + half;
        bool v = slot < total;
        int cidx = kbeg + ((v && slot > 0) ? slot - 1 : 0);
        int cv = col[cidx];
        return (slot == 0 || !v) ? node : cv;
    };

    int s_nxt = srcof(2);
    {
        int s_cur = srcof(0);
        const unsigned short* pc = xlb + (size_t)s_cur * DD + 2 * l;
        // fallthrough into loop with u* preloaded
        unsigned u0 = *(const unsigned*)(pc);
        unsigned u1 = *(const unsigned*)(pc + 64);
        unsigned u2 = *(const unsigned*)(pc + 128);

        for (int i = 0; i < total; i += 2) {
            int s_n2 = srcof(i + 4);
            const unsigned short* pn = xlb + (size_t)s_nxt * DD + 2 * l;
            unsigned n0 = *(const unsigned*)(pn);
            unsigned n1 = *(const unsigned*)(pn + 64);
            unsigned n2 = *(const unsigned*)(pn + 128);

            bool vc = (i + half) < total;
            float a0x = __uint_as_float(u0 << 16), a0y = __uint_as_float(u0 & 0xFFFF0000u);
            float a1x = __uint_as_float(u1 << 16), a1y = __uint_as_float(u1 & 0xFFFF0000u);
            float a2x = __uint_as_float(u2 << 16), a2y = __uint_as_float(u2 & 0xFFFF0000u);
            float m0x = a0x + xr0.x, m0y = a0y + xr0.y;
            float m1x = a1x + xr1.x, m1y = a1y + xr1.y;
            float m2x = a2x + xr2.x, m2y = a2y + xr2.y;
            float p0 = fmaf(w40x, fabsf(m0x), w60x * m0x);
            p0 = fmaf(w60y, m0y, p0); p0 = fmaf(w40y, fabsf(m0y), p0);
            float p1 = fmaf(w41x, fabsf(m1x), w61x * m1x);
            p1 = fmaf(w61y, m1y, p1); p1 = fmaf(w41y, fabsf(m1y), p1);
            float p2 = fmaf(w42x, fabsf(m2x), w62x * m2x);
            p2 = fmaf(w62y, m2y, p2); p2 = fmaf(w42y, fabsf(m2y), p2);
            RED16(p0); RED16(p1); RED16(p2);
            float vf = vc ? 1.f : 0.f;
            float e0 = __expf(p0) * vf, e1 = __expf(p1) * vf, e2 = __expf(p2) * vf;
            den0 += e0; den1 += e1; den2 += e2;
            acc0x = fmaf(e0, a0x, acc0x); acc0y = fmaf(e0, a0y, acc0y);
            acc1x = fmaf(e1, a1x, acc1x); acc1y = fmaf(e1, a1y, acc1y);
            acc2x = fmaf(e2, a2x, acc2x); acc2y = fmaf(e2, a2y, acc2y);

            u0 = n0; u1 = n1; u2 = n2; s_nxt = s_n2;
        }
    }

    // combine the two edge-halves (xor32)
    den0 += __shfl_xor(den0, 32); den1 += __shfl_xor(den1, 32); den2 += __shfl_xor(den2, 32);
    acc0x += __shfl_xor(acc0x, 32); acc0y += __shfl_xor(acc0y, 32);
    acc1x += __shfl_xor(acc1x, 32); acc1y += __shfl_xor(acc1y, 32);
    acc2x += __shfl_xor(acc2x, 32); acc2y += __shfl_xor(acc2y, 32);

    if (half == 0) {
        float i0 = 1.f / (den0 + 1e-16f), i1 = 1.f / (den1 + 1e-16f), i2 = 1.f / (den2 + 1e-16f);
        float2 xv0 = *(const float2*)(x + base + 2 * l);
        float2 xv1 = *(const float2*)(x + base + 64 + 2 * l);
        float2 xv2 = *(const float2*)(x + base + 128 + 2 * l);
        float2 b0 = *(const float2*)(bias + 2 * l);
        float2 b1 = *(const float2*)(bias + 64 + 2 * l);
        float2 b2 = *(const float2*)(bias + 128 + 2 * l);
        float2 o0, o1, o2;
        o0.x = xv0.x + acc0x * i0 + b0.x; o0.x = o0.x > 0.f ? o0.x : 0.f;
        o0.y = xv0.y + acc0y * i0 + b0.y; o0.y = o0.y > 0.f ? o0.y : 0.f;
        o1.x = xv1.x + acc1x * i1 + b1.x; o1.x = o1.x > 0.f ? o1.x : 0.f;
        o1.y = xv1.y + acc1y * i1 + b1.y; o1.y = o1.y > 0.f ? o1.y : 0.f;
        o2.x = xv2.x + acc2x * i2 + b2.x; o2.x = o2.x > 0.f ? o2.x : 0.f;
        o2.y = xv2.y + acc2y * i2 + b2.y; o2.y = o2.y > 0.f ? o2.y : 0.f;
        *(float2*)(out + base + 2 * l)       = o0;
        *(float2*)(out + base + 64 + 2 * l)  = o1;
        *(float2*)(out + base + 128 + 2 * l) = o2;
    }
}

extern "C" void kernel_launch(void* const* d_in, const int* in_sizes, int n_in,
                              void* d_out, int out_size, void* d_ws, size_t ws_size,
                              hipStream_t stream)
{
    const float* x    = (const float*)d_in[0];
    const float* Wl   = (const float*)d_in[1];
    const float* bl   = (const float*)d_in[2];
    const float* Wr   = (const float*)d_in[3];
    const float* br   = (const float*)d_in[4];
    const float* att  = (const float*)d_in[5];
    const float* bias = (const float*)d_in[6];
    const int*   ei   = (const int*)d_in[7];

    const int N = in_sizes[0] / DD;     // 50000
    const int E = in_sizes[7] / 2;      // 800000
    const int nb = ceil_div(N, 256);    // 196 scan blocks

    float* out = (float*)d_out;
    char*  ws  = (char*)d_ws;
    const size_t WSZ = (size_t)DD * DD * sizeof(short);

    size_t off = 0;
    unsigned short* xlb = (unsigned short*)(ws + off); off = alignup(off + (size_t)N * DD * 2);
    short* wlh = (short*)(ws + off); off = alignup(off + WSZ);
    short* wll = (short*)(ws + off); off = alignup(off + WSZ);
    short* wrh = (short*)(ws + off); off = alignup(off + WSZ);
    short* wrl = (short*)(ws + off); off = alignup(off + WSZ);
    int* rowptr = (int*)(ws + off); off = alignup(off + (size_t)(N + 1) * 4);
    int* deg    = (int*)(ws + off); off = alignup(off + (size_t)N * 4);
    int* pos    = (int*)(ws + off); off = alignup(off + (size_t)E * 4);
    int* bsum   = (int*)(ws + off); off = alignup(off + 256 * 4);
    int* col    = (int*)(ws + off); off = alignup(off + (size_t)E * 4 + 256);

    hipMemsetAsync(deg, 0, (size_t)N * sizeof(int), stream);

    conv_w<<<ceil_div(DD * DD, 256), 256, 0, stream>>>(Wl, Wr, wlh, wll, wrh, wrl);
    proj_mfma<<<ceil_div(N, 64), 256, 0, stream>>>(x, wlh, wll, wrh, wrl, bl, br, xlb, out, N);
    deg_kernel<<<ceil_div(E, 256), 256, 0, stream>>>(ei, deg, pos, E);
    scan1<<<nb, 256, 0, stream>>>(deg, bsum, N);
    scan2<<<1, 256, 0, stream>>>(bsum, rowptr, nb, N);
    scan3<<<nb, 256, 0, stream>>>(deg, bsum, rowptr, N);
    scatter_kernel<<<ceil_div(E, 256), 256, 0, stream>>>(ei, rowptr, pos, col, E);
    agg_kernel<<<ceil_div(N, 4), 256, 0, stream>>>(xlb, att, x, bias, rowptr, col, out, N);
}

// Round 5
// 167.918 us; speedup vs baseline: 53.4880x; 1.6000x over previous
//
#include <hip/hip_runtime.h>

#define DD 192
#define NEG 0.2f

typedef float f32x4 __attribute__((ext_vector_type(4)));
typedef short bf16x8 __attribute__((ext_vector_type(8)));
typedef unsigned int u32x4 __attribute__((ext_vector_type(4)));

static inline int ceil_div(int a, int b){ return (a + b - 1) / b; }
static inline size_t alignup(size_t x){ return (x + 511) & ~(size_t)511; }

static __device__ __forceinline__ unsigned short f2bf(float f) {
    unsigned u = __float_as_uint(f);
    u += 0x7FFF + ((u >> 16) & 1);          // round-to-nearest-even
    return (unsigned short)(u >> 16);
}
static __device__ __forceinline__ float bf2f(unsigned short h) {
    return __uint_as_float((unsigned)h << 16);
}

// DPP xor-add within 16-lane rows: masks {1,2,7,15} span the 16-group.
#define DPPA(p, ctrl) do { \
    int _t = __builtin_amdgcn_update_dpp(0, __float_as_int(p), ctrl, 0xf, 0xf, true); \
    (p) += __int_as_float(_t); } while (0)
#define RED16(p) do { DPPA(p,0xB1); DPPA(p,0x4E); DPPA(p,0x141); DPPA(p,0x140); } while (0)

// ---------------------------------------------------------------------------
// conv_w: build combined, pre-swizzled split-W buffer.
// wcomb = 12 slices (one per 16-col tile j) x 12288 ushort (24 KB).
// Within slice j, element for (a, r, k), a in {Lhi,Llo,Rhi,Rlo}:
//   idx = ((a*16 + r)*192 + k) ^ ((r&7)<<3)          (bijective swizzle)
// ---------------------------------------------------------------------------
__global__ __launch_bounds__(256) void conv_w(
    const float* __restrict__ Wl, const float* __restrict__ Wr,
    unsigned short* __restrict__ wcomb)
{
    int i = blockIdx.x * 256 + threadIdx.x;
    if (i >= DD * DD) return;
    int row = i / DD, k = i - row * DD;
    int j = row >> 4, r = row & 15;
    int sw = (r & 7) << 3;
    size_t base = (size_t)j * 12288;

    float f = Wl[i];
    unsigned short h = f2bf(f);
    unsigned short lo = f2bf(f - bf2f(h));
    wcomb[base + (((0 * 16 + r) * 192 + k) ^ sw)] = h;
    wcomb[base + (((1 * 16 + r) * 192 + k) ^ sw)] = lo;
    f = Wr[i];
    h = f2bf(f);
    lo = f2bf(f - bf2f(h));
    wcomb[base + (((2 * 16 + r) * 192 + k) ^ sw)] = h;
    wcomb[base + (((3 * 16 + r) * 192 + k) ^ sw)] = lo;
}

// ---------------------------------------------------------------------------
// Projection via MFMA (bf16x3 split): xl -> bf16 (ws), xr -> f32 (d_out)
// Block = 4 waves x 16 nodes. Double-buffered 24 KB LDS W-slices, reg-staged
// (issue-early/write-late), one barrier per j-tile. ds_read swizzled.
// ---------------------------------------------------------------------------
__global__ __launch_bounds__(256) void proj_mfma(
    const float* __restrict__ x, const unsigned short* __restrict__ wcomb,
    const float* __restrict__ bl, const float* __restrict__ br,
    unsigned short* __restrict__ xlb, float* __restrict__ xr_out, int N)
{
    __shared__ unsigned short wbuf[2][12288];   // 48 KB
    const int t = threadIdx.x;
    const int lane = t & 63;
    int n0 = blockIdx.x * 64 + (t >> 6) * 16;
    if (n0 > N - 16) n0 = N - 16;               // tail waves duplicate (benign)
    const int rr = lane & 15;
    const int kg = lane >> 4;
    const int sw = (rr & 7) << 3;

    const u32x4* wsrc = (const u32x4*)wcomb;    // 16 B units; slice j at j*1536

    // prologue: issue stage loads for slice 0
    u32x4 st[6];
    #pragma unroll
    for (int q = 0; q < 6; ++q) st[q] = wsrc[q * 256 + t];

    // A fragments: load + hi/lo split (long VALU phase hides staging latency)
    bf16x8 ah[6], al[6];
    const float* xrow = x + (size_t)(n0 + rr) * DD + kg * 8;
    #pragma unroll
    for (int s = 0; s < 6; ++s) {
        f32x4 v0 = *(const f32x4*)(xrow + 32 * s);
        f32x4 v1 = *(const f32x4*)(xrow + 32 * s + 4);
        #pragma unroll
        for (int e = 0; e < 8; ++e) {
            float f = (e < 4) ? v0[e] : v1[e - 4];
            unsigned short h = f2bf(f);
            ah[s][e] = (short)h;
            al[s][e] = (short)f2bf(f - bf2f(h));
        }
    }

    #pragma unroll
    for (int q = 0; q < 6; ++q) ((u32x4*)wbuf[0])[q * 256 + t] = st[q];
    __syncthreads();

    #pragma unroll 1
    for (int j = 0; j < 12; ++j) {
        const int cb = j & 1;
        // issue next slice's loads (consumed after compute -> latency hidden)
        if (j < 11) {
            #pragma unroll
            for (int q = 0; q < 6; ++q)
                st[q] = wsrc[(size_t)(j + 1) * 1536 + q * 256 + t];
        }

        // compute j from wbuf[cb]
        f32x4 aL = {0.f, 0.f, 0.f, 0.f};
        f32x4 aR = {0.f, 0.f, 0.f, 0.f};
        const unsigned short* wb = wbuf[cb];
        #pragma unroll
        for (int s = 0; s < 6; ++s) {
            const int ko = kg * 8 + 32 * s;
            bf16x8 bLh = *(const bf16x8*)&wb[( rr        * 192 + ko) ^ sw];
            bf16x8 bLl = *(const bf16x8*)&wb[((16 + rr)  * 192 + ko) ^ sw];
            bf16x8 bRh = *(const bf16x8*)&wb[((32 + rr)  * 192 + ko) ^ sw];
            bf16x8 bRl = *(const bf16x8*)&wb[((48 + rr)  * 192 + ko) ^ sw];
            aL = __builtin_amdgcn_mfma_f32_16x16x32_bf16(ah[s], bLh, aL, 0, 0, 0);
            aR = __builtin_amdgcn_mfma_f32_16x16x32_bf16(ah[s], bRh, aR, 0, 0, 0);
            aL = __builtin_amdgcn_mfma_f32_16x16x32_bf16(al[s], bLh, aL, 0, 0, 0);
            aR = __builtin_amdgcn_mfma_f32_16x16x32_bf16(al[s], bRh, aR, 0, 0, 0);
            aL = __builtin_amdgcn_mfma_f32_16x16x32_bf16(ah[s], bLl, aL, 0, 0, 0);
            aR = __builtin_amdgcn_mfma_f32_16x16x32_bf16(ah[s], bRl, aR, 0, 0, 0);
        }

        // write next slice (s_waitcnt vmcnt lands here, after compute)
        if (j < 11) {
            #pragma unroll
            for (int q = 0; q < 6; ++q) ((u32x4*)wbuf[cb ^ 1])[q * 256 + t] = st[q];
        }

        // epilogue for this col-tile: D col = 16j+rr, D row = n0 + kg*4 + r
        const int col = 16 * j + rr;
        const float bcl = bl[col], bcr = br[col];
        #pragma unroll
        for (int r = 0; r < 4; ++r) {
            size_t o = (size_t)(n0 + kg * 4 + r) * DD + col;
            xlb[o]    = f2bf(aL[r] + bcl);
            xr_out[o] = aR[r] + bcr;
        }
        __syncthreads();
    }
}

// ---------------------------------------------------------------------------
// CSR build: degree+pos -> 3-kernel parallel scan -> atomic-free scatter
// ---------------------------------------------------------------------------
__global__ __launch_bounds__(256) void deg_kernel(
    const int* __restrict__ ei, int* __restrict__ deg, int* __restrict__ pos, int E)
{
    int e = blockIdx.x * 256 + threadIdx.x;
    if (e < E) pos[e] = atomicAdd(&deg[ei[E + e]], 1);
}

__global__ __launch_bounds__(256) void scan1(
    const int* __restrict__ deg, int* __restrict__ bsum, int N)
{
    __shared__ int s[256];
    int t = threadIdx.x, i = blockIdx.x * 256 + t;
    s[t] = (i < N) ? deg[i] : 0;
    __syncthreads();
    for (int o = 128; o > 0; o >>= 1) {
        if (t < o) s[t] += s[t + o];
        __syncthreads();
    }
    if (t == 0) bsum[blockIdx.x] = s[0];
}

__global__ __launch_bounds__(256) void scan2(
    int* __restrict__ bsum, int* __restrict__ rowptr, int nb, int N)
{
    __shared__ int s[256];
    int t = threadIdx.x;
    int v = (t < nb) ? bsum[t] : 0;
    s[t] = v;
    __syncthreads();
    for (int o = 1; o < 256; o <<= 1) {
        int u = (t >= o) ? s[t - o] : 0;
        __syncthreads();
        s[t] += u;
        __syncthreads();
    }
    if (t < nb) bsum[t] = s[t] - v;       // exclusive block prefix
    if (t == 255) rowptr[N] = s[255];     // total = E
}

__global__ __launch_bounds__(256) void scan3(
    const int* __restrict__ deg, const int* __restrict__ bsum,
    int* __restrict__ rowptr, int N)
{
    __shared__ int s[256];
    int t = threadIdx.x, i = blockIdx.x * 256 + t;
    int v = (i < N) ? deg[i] : 0;
    s[t] = v;
    __syncthreads();
    for (int o = 1; o < 256; o <<= 1) {
        int u = (t >= o) ? s[t - o] : 0;
        __syncthreads();
        s[t] += u;
        __syncthreads();
    }
    if (i < N) rowptr[i] = bsum[blockIdx.x] + s[t] - v;
}

__global__ __launch_bounds__(256) void scatter_kernel(
    const int* __restrict__ ei, const int* __restrict__ rowptr,
    const int* __restrict__ pos, int* __restrict__ col, int E)
{
    int e = blockIdx.x * 256 + threadIdx.x;
    if (e >= E) return;
    col[rowptr[ei[E + e]] + pos[e]] = ei[e];
}

// ---------------------------------------------------------------------------
// Pull aggregation: one wave per dst node, TWO edges per iteration
// (lanes 0-31 edge A, 32-63 edge B). Lane owns dim-pairs; each head = one
// 16-lane group -> 4-step DPP reduce. Pipelined gathers. Fused epilogue.
// ---------------------------------------------------------------------------
__global__ __launch_bounds__(256) void agg_kernel(
    const unsigned short* __restrict__ xlb, const float* __restrict__ att,
    const float* __restrict__ x, const float* __restrict__ bias,
    const int* __restrict__ rowptr, const int* __restrict__ col,
    float* __restrict__ out, int N)
{
    const int node = blockIdx.x * 4 + (threadIdx.x >> 6);
    if (node >= N) return;
    const int lane = threadIdx.x & 63;
    const int l    = lane & 31;
    const int half = lane >> 5;
    const size_t base = (size_t)node * DD;

    const float2 xr0 = *(const float2*)(out + base + 2 * l);
    const float2 xr1 = *(const float2*)(out + base + 64 + 2 * l);
    const float2 xr2 = *(const float2*)(out + base + 128 + 2 * l);
    const float2 wv0 = *(const float2*)(att + 2 * l);
    const float2 wv1 = *(const float2*)(att + 64 + 2 * l);
    const float2 wv2 = *(const float2*)(att + 128 + 2 * l);
    const float w60x = 0.6f * wv0.x, w40x = 0.4f * wv0.x, w60y = 0.6f * wv0.y, w40y = 0.4f * wv0.y;
    const float w61x = 0.6f * wv1.x, w41x = 0.4f * wv1.x, w61y = 0.6f * wv1.y, w41y = 0.4f * wv1.y;
    const float w62x = 0.6f * wv2.x, w42x = 0.4f * wv2.x, w62y = 0.6f * wv2.y, w42y = 0.4f * wv2.y;

    float acc0x = 0.f, acc0y = 0.f, acc1x = 0.f, acc1y = 0.f, acc2x = 0.f, acc2y = 0.f;
    float den0 = 0.f, den1 = 0.f, den2 = 0.f;

    const int kbeg  = rowptr[node];
    const int total = rowptr[node + 1] - kbeg + 1;    // self + deg

    auto srcof = [&](int i) -> int {
        int slot = i + half;
        bool v = slot < total;
        int cidx = kbeg + ((v && slot > 0) ? slot - 1 : 0);
        int cv = col[cidx];
        return (slot == 0 || !v) ? node : cv;
    };

    int s_nxt = srcof(2);
    {
        int s_cur = srcof(0);
        const unsigned short* pc = xlb + (size_t)s_cur * DD + 2 * l;
        unsigned u0 = *(const unsigned*)(pc);
        unsigned u1 = *(const unsigned*)(pc + 64);
        unsigned u2 = *(const unsigned*)(pc + 128);

        for (int i = 0; i < total; i += 2) {
            int s_n2 = srcof(i + 4);
            const unsigned short* pn = xlb + (size_t)s_nxt * DD + 2 * l;
            unsigned n0 = *(const unsigned*)(pn);
            unsigned n1 = *(const unsigned*)(pn + 64);
            unsigned n2 = *(const unsigned*)(pn + 128);

            bool vc = (i + half) < total;
            float a0x = __uint_as_float(u0 << 16), a0y = __uint_as_float(u0 & 0xFFFF0000u);
            float a1x = __uint_as_float(u1 << 16), a1y = __uint_as_float(u1 & 0xFFFF0000u);
            float a2x = __uint_as_float(u2 << 16), a2y = __uint_as_float(u2 & 0xFFFF0000u);
            float m0x = a0x + xr0.x, m0y = a0y + xr0.y;
            float m1x = a1x + xr1.x, m1y = a1y + xr1.y;
            float m2x = a2x + xr2.x, m2y = a2y + xr2.y;
            float p0 = fmaf(w40x, fabsf(m0x), w60x * m0x);
            p0 = fmaf(w60y, m0y, p0); p0 = fmaf(w40y, fabsf(m0y), p0);
            float p1 = fmaf(w41x, fabsf(m1x), w61x * m1x);
            p1 = fmaf(w61y, m1y, p1); p1 = fmaf(w41y, fabsf(m1y), p1);
            float p2 = fmaf(w42x, fabsf(m2x), w62x * m2x);
            p2 = fmaf(w62y, m2y, p2); p2 = fmaf(w42y, fabsf(m2y), p2);
            RED16(p0); RED16(p1); RED16(p2);
            float vf = vc ? 1.f : 0.f;
            float e0 = __expf(p0) * vf, e1 = __expf(p1) * vf, e2 = __expf(p2) * vf;
            den0 += e0; den1 += e1; den2 += e2;
            acc0x = fmaf(e0, a0x, acc0x); acc0y = fmaf(e0, a0y, acc0y);
            acc1x = fmaf(e1, a1x, acc1x); acc1y = fmaf(e1, a1y, acc1y);
            acc2x = fmaf(e2, a2x, acc2x); acc2y = fmaf(e2, a2y, acc2y);

            u0 = n0; u1 = n1; u2 = n2; s_nxt = s_n2;
        }
    }

    den0 += __shfl_xor(den0, 32); den1 += __shfl_xor(den1, 32); den2 += __shfl_xor(den2, 32);
    acc0x += __shfl_xor(acc0x, 32); acc0y += __shfl_xor(acc0y, 32);
    acc1x += __shfl_xor(acc1x, 32); acc1y += __shfl_xor(acc1y, 32);
    acc2x += __shfl_xor(acc2x, 32); acc2y += __shfl_xor(acc2y, 32);

    if (half == 0) {
        float i0 = 1.f / (den0 + 1e-16f), i1 = 1.f / (den1 + 1e-16f), i2 = 1.f / (den2 + 1e-16f);
        float2 xv0 = *(const float2*)(x + base + 2 * l);
        float2 xv1 = *(const float2*)(x + base + 64 + 2 * l);
        float2 xv2 = *(const float2*)(x + base + 128 + 2 * l);
        float2 b0 = *(const float2*)(bias + 2 * l);
        float2 b1 = *(const float2*)(bias + 64 + 2 * l);
        float2 b2 = *(const float2*)(bias + 128 + 2 * l);
        float2 o0, o1, o2;
        o0.x = xv0.x + acc0x * i0 + b0.x; o0.x = o0.x > 0.f ? o0.x : 0.f;
        o0.y = xv0.y + acc0y * i0 + b0.y; o0.y = o0.y > 0.f ? o0.y : 0.f;
        o1.x = xv1.x + acc1x * i1 + b1.x; o1.x = o1.x > 0.f ? o1.x : 0.f;
        o1.y = xv1.y + acc1y * i1 + b1.y; o1.y = o1.y > 0.f ? o1.y : 0.f;
        o2.x = xv2.x + acc2x * i2 + b2.x; o2.x = o2.x > 0.f ? o2.x : 0.f;
        o2.y = xv2.y + acc2y * i2 + b2.y; o2.y = o2.y > 0.f ? o2.y : 0.f;
        *(float2*)(out + base + 2 * l)       = o0;
        *(float2*)(out + base + 64 + 2 * l)  = o1;
        *(float2*)(out + base + 128 + 2 * l) = o2;
    }
}

extern "C" void kernel_launch(void* const* d_in, const int* in_sizes, int n_in,
                              void* d_out, int out_size, void* d_ws, size_t ws_size,
                              hipStream_t stream)
{
    const float* x    = (const float*)d_in[0];
    const float* Wl   = (const float*)d_in[1];
    const float* bl   = (const float*)d_in[2];
    const float* Wr   = (const float*)d_in[3];
    const float* br   = (const float*)d_in[4];
    const float* att  = (const float*)d_in[5];
    const float* bias = (const float*)d_in[6];
    const int*   ei   = (const int*)d_in[7];

    const int N = in_sizes[0] / DD;     // 50000
    const int E = in_sizes[7] / 2;      // 800000
    const int nb = ceil_div(N, 256);    // scan blocks

    float* out = (float*)d_out;
    char*  ws  = (char*)d_ws;

    size_t off = 0;
    unsigned short* xlb   = (unsigned short*)(ws + off); off = alignup(off + (size_t)N * DD * 2);
    unsigned short* wcomb = (unsigned short*)(ws + off); off = alignup(off + (size_t)12 * 12288 * 2);
    int* rowptr = (int*)(ws + off); off = alignup(off + (size_t)(N + 1) * 4);
    int* deg    = (int*)(ws + off); off = alignup(off + (size_t)N * 4);
    int* pos    = (int*)(ws + off); off = alignup(off + (size_t)E * 4);
    int* bsum   = (int*)(ws + off); off = alignup(off + 256 * 4);
    int* col    = (int*)(ws + off); off = alignup(off + (size_t)E * 4 + 256);

    hipMemsetAsync(deg, 0, (size_t)N * sizeof(int), stream);

    conv_w<<<ceil_div(DD * DD, 256), 256, 0, stream>>>(Wl, Wr, wcomb);
    proj_mfma<<<ceil_div(N, 64), 256, 0, stream>>>(x, wcomb, bl, br, xlb, out, N);
    deg_kernel<<<ceil_div(E, 256), 256, 0, stream>>>(ei, deg, pos, E);
    scan1<<<nb, 256, 0, stream>>>(deg, bsum, N);
    scan2<<<1, 256, 0, stream>>>(bsum, rowptr, nb, N);
    scan3<<<nb, 256, 0, stream>>>(deg, bsum, rowptr, N);
    scatter_kernel<<<ceil_div(E, 256), 256, 0, stream>>>(ei, rowptr, pos, col, E);
    agg_kernel<<<ceil_div(N, 4), 256, 0, stream>>>(xlb, att, x, bias, rowptr, col, out, N);
}

// Round 7
// 165.976 us; speedup vs baseline: 54.1141x; 1.0117x over previous
//
#include <hip/hip_runtime.h>

#define DD 192
#define NEG 0.2f

typedef float f32x4 __attribute__((ext_vector_type(4)));
typedef short bf16x8 __attribute__((ext_vector_type(8)));
typedef unsigned int u32x4 __attribute__((ext_vector_type(4)));
typedef __fp16 h2 __attribute__((ext_vector_type(2)));

static inline int ceil_div(int a, int b){ return (a + b - 1) / b; }
static inline size_t alignup(size_t x){ return (x + 511) & ~(size_t)511; }

static __device__ __forceinline__ unsigned short f2bf(float f) {
    unsigned u = __float_as_uint(f);
    u += 0x7FFF + ((u >> 16) & 1);          // round-to-nearest-even
    return (unsigned short)(u >> 16);
}
static __device__ __forceinline__ float bf2f(unsigned short h) {
    return __uint_as_float((unsigned)h << 16);
}
static __device__ __forceinline__ h2 as_h2(unsigned u){ union{unsigned i; h2 h;} c; c.i=u; return c.h; }
static __device__ __forceinline__ unsigned as_u(h2 h){ union{h2 h; unsigned i;} c; c.h=h; return c.i; }

// DPP xor-add; RED8 sums within each 8-lane group: xor1, xor2, half-mirror.
#define DPPA(p, ctrl) do { \
    int _t = __builtin_amdgcn_update_dpp(0, __float_as_int(p), ctrl, 0xf, 0xf, true); \
    (p) += __int_as_float(_t); } while (0)
#define RED8(p) do { DPPA(p,0xB1); DPPA(p,0x4E); DPPA(p,0x141); } while (0)

// ---------------------------------------------------------------------------
// conv_w: combined, pre-swizzled split-W buffer (bf16 hi/lo for MFMA).
// ---------------------------------------------------------------------------
__global__ __launch_bounds__(256) void conv_w(
    const float* __restrict__ Wl, const float* __restrict__ Wr,
    unsigned short* __restrict__ wcomb)
{
    int i = blockIdx.x * 256 + threadIdx.x;
    if (i >= DD * DD) return;
    int row = i / DD, k = i - row * DD;
    int j = row >> 4, r = row & 15;
    int sw = (r & 7) << 3;
    size_t base = (size_t)j * 12288;

    float f = Wl[i];
    unsigned short h = f2bf(f);
    unsigned short lo = f2bf(f - bf2f(h));
    wcomb[base + (((0 * 16 + r) * 192 + k) ^ sw)] = h;
    wcomb[base + (((1 * 16 + r) * 192 + k) ^ sw)] = lo;
    f = Wr[i];
    h = f2bf(f);
    lo = f2bf(f - bf2f(h));
    wcomb[base + (((2 * 16 + r) * 192 + k) ^ sw)] = h;
    wcomb[base + (((3 * 16 + r) * 192 + k) ^ sw)] = lo;
}

// ---------------------------------------------------------------------------
// Projection via MFMA (bf16x3 split): xl -> fp16 (ws), xr -> f32 (d_out)
// ---------------------------------------------------------------------------
__global__ __launch_bounds__(256) void proj_mfma(
    const float* __restrict__ x, const unsigned short* __restrict__ wcomb,
    const float* __restrict__ bl, const float* __restrict__ br,
    __fp16* __restrict__ xlh, float* __restrict__ xr_out, int N)
{
    __shared__ unsigned short wbuf[2][12288];   // 48 KB
    const int t = threadIdx.x;
    const int lane = t & 63;
    int n0 = blockIdx.x * 64 + (t >> 6) * 16;
    if (n0 > N - 16) n0 = N - 16;
    const int rr = lane & 15;
    const int kg = lane >> 4;
    const int sw = (rr & 7) << 3;

    const u32x4* wsrc = (const u32x4*)wcomb;

    u32x4 st[6];
    #pragma unroll
    for (int q = 0; q < 6; ++q) st[q] = wsrc[q * 256 + t];

    bf16x8 ah[6], al[6];
    const float* xrow = x + (size_t)(n0 + rr) * DD + kg * 8;
    #pragma unroll
    for (int s = 0; s < 6; ++s) {
        f32x4 v0 = *(const f32x4*)(xrow + 32 * s);
        f32x4 v1 = *(const f32x4*)(xrow + 32 * s + 4);
        #pragma unroll
        for (int e = 0; e < 8; ++e) {
            float f = (e < 4) ? v0[e] : v1[e - 4];
            unsigned short h = f2bf(f);
            ah[s][e] = (short)h;
            al[s][e] = (short)f2bf(f - bf2f(h));
        }
    }

    #pragma unroll
    for (int q = 0; q < 6; ++q) ((u32x4*)wbuf[0])[q * 256 + t] = st[q];
    __syncthreads();

    #pragma unroll 1
    for (int j = 0; j < 12; ++j) {
        const int cb = j & 1;
        if (j < 11) {
            #pragma unroll
            for (int q = 0; q < 6; ++q)
                st[q] = wsrc[(size_t)(j + 1) * 1536 + q * 256 + t];
        }

        f32x4 aL = {0.f, 0.f, 0.f, 0.f};
        f32x4 aR = {0.f, 0.f, 0.f, 0.f};
        const unsigned short* wb = wbuf[cb];
        #pragma unroll
        for (int s = 0; s < 6; ++s) {
            const int ko = kg * 8 + 32 * s;
            bf16x8 bLh = *(const bf16x8*)&wb[( rr        * 192 + ko) ^ sw];
            bf16x8 bLl = *(const bf16x8*)&wb[((16 + rr)  * 192 + ko) ^ sw];
            bf16x8 bRh = *(const bf16x8*)&wb[((32 + rr)  * 192 + ko) ^ sw];
            bf16x8 bRl = *(const bf16x8*)&wb[((48 + rr)  * 192 + ko) ^ sw];
            aL = __builtin_amdgcn_mfma_f32_16x16x32_bf16(ah[s], bLh, aL, 0, 0, 0);
            aR = __builtin_amdgcn_mfma_f32_16x16x32_bf16(ah[s], bRh, aR, 0, 0, 0);
            aL = __builtin_amdgcn_mfma_f32_16x16x32_bf16(al[s], bLh, aL, 0, 0, 0);
            aR = __builtin_amdgcn_mfma_f32_16x16x32_bf16(al[s], bRh, aR, 0, 0, 0);
            aL = __builtin_amdgcn_mfma_f32_16x16x32_bf16(ah[s], bLl, aL, 0, 0, 0);
            aR = __builtin_amdgcn_mfma_f32_16x16x32_bf16(ah[s], bRl, aR, 0, 0, 0);
        }

        if (j < 11) {
            #pragma unroll
            for (int q = 0; q < 6; ++q) ((u32x4*)wbuf[cb ^ 1])[q * 256 + t] = st[q];
        }

        const int col = 16 * j + rr;
        const float bcl = bl[col], bcr = br[col];
        #pragma unroll
        for (int r = 0; r < 4; ++r) {
            size_t o = (size_t)(n0 + kg * 4 + r) * DD + col;
            xlh[o]    = (__fp16)(aL[r] + bcl);
            xr_out[o] = aR[r] + bcr;
        }
        __syncthreads();
    }
}

// ---------------------------------------------------------------------------
// CSR build: degree+pos -> 3-kernel parallel scan -> atomic-free scatter
// ---------------------------------------------------------------------------
__global__ __launch_bounds__(256) void deg_kernel(
    const int* __restrict__ ei, int* __restrict__ deg, int* __restrict__ pos, int E)
{
    int e = blockIdx.x * 256 + threadIdx.x;
    if (e < E) pos[e] = atomicAdd(&deg[ei[E + e]], 1);
}

__global__ __launch_bounds__(256) void scan1(
    const int* __restrict__ deg, int* __restrict__ bsum, int N)
{
    __shared__ int s[256];
    int t = threadIdx.x, i = blockIdx.x * 256 + t;
    s[t] = (i < N) ? deg[i] : 0;
    __syncthreads();
    for (int o = 128; o > 0; o >>= 1) {
        if (t < o) s[t] += s[t + o];
        __syncthreads();
    }
    if (t == 0) bsum[blockIdx.x] = s[0];
}

__global__ __launch_bounds__(256) void scan2(
    int* __restrict__ bsum, int* __restrict__ rowptr, int nb, int N)
{
    __shared__ int s[256];
    int t = threadIdx.x;
    int v = (t < nb) ? bsum[t] : 0;
    s[t] = v;
    __syncthreads();
    for (int o = 1; o < 256; o <<= 1) {
        int u = (t >= o) ? s[t - o] : 0;
        __syncthreads();
        s[t] += u;
        __syncthreads();
    }
    if (t < nb) bsum[t] = s[t] - v;
    if (t == 255) rowptr[N] = s[255];
}

__global__ __launch_bounds__(256) void scan3(
    const int* __restrict__ deg, const int* __restrict__ bsum,
    int* __restrict__ rowptr, int N)
{
    __shared__ int s[256];
    int t = threadIdx.x, i = blockIdx.x * 256 + t;
    int v = (i < N) ? deg[i] : 0;
    s[t] = v;
    __syncthreads();
    for (int o = 1; o < 256; o <<= 1) {
        int u = (t >= o) ? s[t - o] : 0;
        __syncthreads();
        s[t] += u;
        __syncthreads();
    }
    if (i < N) rowptr[i] = bsum[blockIdx.x] + s[t] - v;
}

__global__ __launch_bounds__(256) void scatter_kernel(
    const int* __restrict__ ei, const int* __restrict__ rowptr,
    const int* __restrict__ pos, int* __restrict__ col, int E)
{
    int e = blockIdx.x * 256 + threadIdx.x;
    if (e >= E) return;
    col[rowptr[ei[E + e]] + pos[e]] = ei[e];
}

// ---------------------------------------------------------------------------
// Pull aggregation: one wave per dst node, FOUR edges per iteration
// (16 lanes per edge; lane owns dims [64s+4*l16, +4) for s=0..2).
// fp16 packed: pk_add + sign-mask + 2x fdot2 per pair (lrelu & log2e folded
// into w6/w4); 3-step DPP reduce per 8-lane head group; exp2; mixed fma acc.
// ---------------------------------------------------------------------------
__global__ __launch_bounds__(256) void agg_kernel(
    const __fp16* __restrict__ xlh, const float* __restrict__ att,
    const float* __restrict__ x, const float* __restrict__ bias,
    const int* __restrict__ rowptr, const int* __restrict__ col,
    float* __restrict__ out, int N)
{
    const int node = blockIdx.x * 4 + (threadIdx.x >> 6);
    if (node >= N) return;
    const int lane = threadIdx.x & 63;
    const int l16  = lane & 15;
    const int q    = lane >> 4;          // edge slot 0..3
    const float LOG2E = 1.4426950408889634f;

    h2 xrh[3][2], w6[3][2], w4[3][2];
    #pragma unroll
    for (int s = 0; s < 3; ++s) {
        f32x4 xv = *(const f32x4*)(out + (size_t)node * DD + 64 * s + 4 * l16);
        xrh[s][0] = __builtin_amdgcn_cvt_pkrtz(xv[0], xv[1]);
        xrh[s][1] = __builtin_amdgcn_cvt_pkrtz(xv[2], xv[3]);
        f32x4 wv = *(const f32x4*)(att + 64 * s + 4 * l16);
        w6[s][0] = __builtin_amdgcn_cvt_pkrtz(0.6f * LOG2E * wv[0], 0.6f * LOG2E * wv[1]);
        w6[s][1] = __builtin_amdgcn_cvt_pkrtz(0.6f * LOG2E * wv[2], 0.6f * LOG2E * wv[3]);
        w4[s][0] = __builtin_amdgcn_cvt_pkrtz(0.4f * LOG2E * wv[0], 0.4f * LOG2E * wv[1]);
        w4[s][1] = __builtin_amdgcn_cvt_pkrtz(0.4f * LOG2E * wv[2], 0.4f * LOG2E * wv[3]);
    }

    float acc[3][4] = {{0.f,0.f,0.f,0.f},{0.f,0.f,0.f,0.f},{0.f,0.f,0.f,0.f}};
    float den[3] = {0.f, 0.f, 0.f};

    const int kbeg  = rowptr[node];
    const int total = rowptr[node + 1] - kbeg + 1;    // self + deg

    auto srcat = [&](int slot) -> int {
        bool v = slot < total;
        int cidx = kbeg + ((v && slot > 0) ? slot - 1 : 0);
        int cv = col[cidx];
        return (slot == 0 || !v) ? node : cv;
    };

    uint2 cur0, cur1, cur2, nxt0, nxt1, nxt2;
    {
        int s0 = srcat(q);
        const char* pc = (const char*)xlh + (size_t)s0 * 384 + 8 * l16;
        cur0 = *(const uint2*)(pc);
        cur1 = *(const uint2*)(pc + 128);
        cur2 = *(const uint2*)(pc + 256);
    }
    int s_nxt = srcat(4 + q);

    for (int i = 0; i < total; i += 4) {
        int s_n2 = srcat(i + 8 + q);
        const char* pn = (const char*)xlh + (size_t)s_nxt * 384 + 8 * l16;
        nxt0 = *(const uint2*)(pn);
        nxt1 = *(const uint2*)(pn + 128);
        nxt2 = *(const uint2*)(pn + 256);

        const bool vc = (i + q) < total;
        #pragma unroll
        for (int s = 0; s < 3; ++s) {
            const uint2 cu = (s == 0) ? cur0 : (s == 1) ? cur1 : cur2;
            h2 a0 = as_h2(cu.x), a1 = as_h2(cu.y);
            h2 u0 = a0 + xrh[s][0], u1 = a1 + xrh[s][1];
            h2 b0 = as_h2(as_u(u0) & 0x7FFF7FFFu);   // |u| packed
            h2 b1 = as_h2(as_u(u1) & 0x7FFF7FFFu);
            float p = __builtin_amdgcn_fdot2(u0, w6[s][0], 0.f, false);
            p = __builtin_amdgcn_fdot2(b0, w4[s][0], p, false);
            p = __builtin_amdgcn_fdot2(u1, w6[s][1], p, false);
            p = __builtin_amdgcn_fdot2(b1, w4[s][1], p, false);
            RED8(p);
            p = vc ? p : -1e30f;
            float e = exp2f(p);
            den[s] += e;
            acc[s][0] = fmaf((float)a0.x, e, acc[s][0]);
            acc[s][1] = fmaf((float)a0.y, e, acc[s][1]);
            acc[s][2] = fmaf((float)a1.x, e, acc[s][2]);
            acc[s][3] = fmaf((float)a1.y, e, acc[s][3]);
        }
        cur0 = nxt0; cur1 = nxt1; cur2 = nxt2;
        s_nxt = s_n2;
    }

    // combine the four edge slots
    #pragma unroll
    for (int s = 0; s < 3; ++s) {
        den[s] += __shfl_xor(den[s], 16); den[s] += __shfl_xor(den[s], 32);
        #pragma unroll
        for (int j = 0; j < 4; ++j) {
            acc[s][j] += __shfl_xor(acc[s][j], 16);
            acc[s][j] += __shfl_xor(acc[s][j], 32);
        }
    }

    if (q == 0) {
        #pragma unroll
        for (int s = 0; s < 3; ++s) {
            float inv = __builtin_amdgcn_rcpf(den[s] + 1e-16f);
            f32x4 xv = *(const f32x4*)(x + (size_t)node * DD + 64 * s + 4 * l16);
            f32x4 bv = *(const f32x4*)(bias + 64 * s + 4 * l16);
            f32x4 o;
            #pragma unroll
            for (int j = 0; j < 4; ++j) {
                float v = fmaf(acc[s][j], inv, xv[j] + bv[j]);
                o[j] = v > 0.f ? v : 0.f;
            }
            *(f32x4*)(out + (size_t)node * DD + 64 * s + 4 * l16) = o;
        }
    }
}

extern "C" void kernel_launch(void* const* d_in, const int* in_sizes, int n_in,
                              void* d_out, int out_size, void* d_ws, size_t ws_size,
                              hipStream_t stream)
{
    const float* x    = (const float*)d_in[0];
    const float* Wl   = (const float*)d_in[1];
    const float* bl   = (const float*)d_in[2];
    const float* Wr   = (const float*)d_in[3];
    const float* br   = (const float*)d_in[4];
    const float* att  = (const float*)d_in[5];
    const float* bias = (const float*)d_in[6];
    const int*   ei   = (const int*)d_in[7];

    const int N = in_sizes[0] / DD;     // 50000
    const int E = in_sizes[7] / 2;      // 800000
    const int nb = ceil_div(N, 256);    // scan blocks

    float* out = (float*)d_out;
    char*  ws  = (char*)d_ws;

    size_t off = 0;
    __fp16* xlh = (__fp16*)(ws + off); off = alignup(off + (size_t)N * DD * 2);
    unsigned short* wcomb = (unsigned short*)(ws + off); off = alignup(off + (size_t)12 * 12288 * 2);
    int* rowptr = (int*)(ws + off); off = alignup(off + (size_t)(N + 1) * 4);
    int* deg    = (int*)(ws + off); off = alignup(off + (size_t)N * 4);
    int* pos    = (int*)(ws + off); off = alignup(off + (size_t)E * 4);
    int* bsum   = (int*)(ws + off); off = alignup(off + 256 * 4);
    int* col    = (int*)(ws + off); off = alignup(off + (size_t)E * 4 + 256);

    hipMemsetAsync(deg, 0, (size_t)N * sizeof(int), stream);

    conv_w<<<ceil_div(DD * DD, 256), 256, 0, stream>>>(Wl, Wr, wcomb);
    proj_mfma<<<ceil_div(N, 64), 256, 0, stream>>>(x, wcomb, bl, br, xlh, out, N);
    deg_kernel<<<ceil_div(E, 256), 256, 0, stream>>>(ei, deg, pos, E);
    scan1<<<nb, 256, 0, stream>>>(deg, bsum, N);
    scan2<<<1, 256, 0, stream>>>(bsum, rowptr, nb, N);
    scan3<<<nb, 256, 0, stream>>>(deg, bsum, rowptr, N);
    scatter_kernel<<<ceil_div(E, 256), 256, 0, stream>>>(ei, rowptr, pos, col, E);
    agg_kernel<<<ceil_div(N, 4), 256, 0, stream>>>(xlh, att, x, bias, rowptr, col, out, N);
}

// Round 8
// 163.465 us; speedup vs baseline: 54.9451x; 1.0154x over previous
//
#include <hip/hip_runtime.h>

#define DD 192
#define NEG 0.2f

typedef float f32x4 __attribute__((ext_vector_type(4)));
typedef short bf16x8 __attribute__((ext_vector_type(8)));
typedef unsigned int u32x4 __attribute__((ext_vector_type(4)));
typedef __fp16 h2 __attribute__((ext_vector_type(2)));

static inline int ceil_div(int a, int b){ return (a + b - 1) / b; }
static inline size_t alignup(size_t x){ return (x + 511) & ~(size_t)511; }

static __device__ __forceinline__ unsigned short f2bf(float f) {
    unsigned u = __float_as_uint(f);
    u += 0x7FFF + ((u >> 16) & 1);          // round-to-nearest-even
    return (unsigned short)(u >> 16);
}
static __device__ __forceinline__ float bf2f(unsigned short h) {
    return __uint_as_float((unsigned)h << 16);
}
static __device__ __forceinline__ h2 as_h2(unsigned u){ union{unsigned i; h2 h;} c; c.i=u; return c.h; }
static __device__ __forceinline__ unsigned as_u(h2 h){ union{h2 h; unsigned i;} c; c.h=h; return c.i; }

// DPP xor-add; RED8 sums within each 8-lane group: xor1, xor2, half-mirror.
#define DPPA(p, ctrl) do { \
    int _t = __builtin_amdgcn_update_dpp(0, __float_as_int(p), ctrl, 0xf, 0xf, true); \
    (p) += __int_as_float(_t); } while (0)
#define RED8(p) do { DPPA(p,0xB1); DPPA(p,0x4E); DPPA(p,0x141); } while (0)

// ---------------------------------------------------------------------------
// K1: conv_w (blocks [0,convB)) ∥ deg/pos histogram (blocks [convB,...))
// ---------------------------------------------------------------------------
__global__ __launch_bounds__(256) void k1_convw_deg(
    const float* __restrict__ Wl, const float* __restrict__ Wr,
    unsigned short* __restrict__ wcomb,
    const int* __restrict__ ei, int* __restrict__ deg, int* __restrict__ pos,
    int E, int convB)
{
    const int b = blockIdx.x, t = threadIdx.x;
    if (b < convB) {
        int i = b * 256 + t;
        if (i >= DD * DD) return;
        int row = i / DD, k = i - row * DD;
        int j = row >> 4, r = row & 15;
        int sw = (r & 7) << 3;
        size_t base = (size_t)j * 12288;
        float f = Wl[i];
        unsigned short h = f2bf(f);
        unsigned short lo = f2bf(f - bf2f(h));
        wcomb[base + (((0 * 16 + r) * 192 + k) ^ sw)] = h;
        wcomb[base + (((1 * 16 + r) * 192 + k) ^ sw)] = lo;
        f = Wr[i];
        h = f2bf(f);
        lo = f2bf(f - bf2f(h));
        wcomb[base + (((2 * 16 + r) * 192 + k) ^ sw)] = h;
        wcomb[base + (((3 * 16 + r) * 192 + k) ^ sw)] = lo;
    } else {
        int e = (b - convB) * 256 + t;
        if (e < E) pos[e] = atomicAdd(&deg[ei[E + e]], 1);
    }
}

// ---------------------------------------------------------------------------
// K2: proj_mfma (blocks [0,projB)) ∥ scan1 block sums (blocks [projB,...))
// ---------------------------------------------------------------------------
__global__ __launch_bounds__(256) void k2_proj_scan1(
    const float* __restrict__ x, const unsigned short* __restrict__ wcomb,
    const float* __restrict__ bl, const float* __restrict__ br,
    __fp16* __restrict__ xlh, float* __restrict__ xr_out, int N,
    const int* __restrict__ deg, int* __restrict__ bsum, int projB)
{
    __shared__ unsigned short wbuf[2][12288];   // 48 KB (proj branch)
    __shared__ int ssum[256];                   // scan1 branch
    const int t = threadIdx.x;

    if ((int)blockIdx.x >= projB) {
        // ---- scan1: per-256-chunk degree sums ----
        int bid = blockIdx.x - projB;
        int i = bid * 256 + t;
        ssum[t] = (i < N) ? deg[i] : 0;
        __syncthreads();
        for (int o = 128; o > 0; o >>= 1) {
            if (t < o) ssum[t] += ssum[t + o];
            __syncthreads();
        }
        if (t == 0) bsum[bid] = ssum[0];
        return;
    }

    // ---- proj ----
    const int lane = t & 63;
    int n0 = blockIdx.x * 64 + (t >> 6) * 16;
    if (n0 > N - 16) n0 = N - 16;
    const int rr = lane & 15;
    const int kg = lane >> 4;
    const int sw = (rr & 7) << 3;

    const u32x4* wsrc = (const u32x4*)wcomb;

    u32x4 st[6];
    #pragma unroll
    for (int q = 0; q < 6; ++q) st[q] = wsrc[q * 256 + t];

    bf16x8 ah[6], al[6];
    const float* xrow = x + (size_t)(n0 + rr) * DD + kg * 8;
    #pragma unroll
    for (int s = 0; s < 6; ++s) {
        f32x4 v0 = *(const f32x4*)(xrow + 32 * s);
        f32x4 v1 = *(const f32x4*)(xrow + 32 * s + 4);
        #pragma unroll
        for (int e = 0; e < 8; ++e) {
            float f = (e < 4) ? v0[e] : v1[e - 4];
            unsigned short h = f2bf(f);
            ah[s][e] = (short)h;
            al[s][e] = (short)f2bf(f - bf2f(h));
        }
    }

    #pragma unroll
    for (int q = 0; q < 6; ++q) ((u32x4*)wbuf[0])[q * 256 + t] = st[q];
    __syncthreads();

    #pragma unroll 1
    for (int j = 0; j < 12; ++j) {
        const int cb = j & 1;
        if (j < 11) {
            #pragma unroll
            for (int q = 0; q < 6; ++q)
                st[q] = wsrc[(size_t)(j + 1) * 1536 + q * 256 + t];
        }

        f32x4 aL = {0.f, 0.f, 0.f, 0.f};
        f32x4 aR = {0.f, 0.f, 0.f, 0.f};
        const unsigned short* wb = wbuf[cb];
        #pragma unroll
        for (int s = 0; s < 6; ++s) {
            const int ko = kg * 8 + 32 * s;
            bf16x8 bLh = *(const bf16x8*)&wb[( rr        * 192 + ko) ^ sw];
            bf16x8 bLl = *(const bf16x8*)&wb[((16 + rr)  * 192 + ko) ^ sw];
            bf16x8 bRh = *(const bf16x8*)&wb[((32 + rr)  * 192 + ko) ^ sw];
            bf16x8 bRl = *(const bf16x8*)&wb[((48 + rr)  * 192 + ko) ^ sw];
            aL = __builtin_amdgcn_mfma_f32_16x16x32_bf16(ah[s], bLh, aL, 0, 0, 0);
            aR = __builtin_amdgcn_mfma_f32_16x16x32_bf16(ah[s], bRh, aR, 0, 0, 0);
            aL = __builtin_amdgcn_mfma_f32_16x16x32_bf16(al[s], bLh, aL, 0, 0, 0);
            aR = __builtin_amdgcn_mfma_f32_16x16x32_bf16(al[s], bRh, aR, 0, 0, 0);
            aL = __builtin_amdgcn_mfma_f32_16x16x32_bf16(ah[s], bLl, aL, 0, 0, 0);
            aR = __builtin_amdgcn_mfma_f32_16x16x32_bf16(ah[s], bRl, aR, 0, 0, 0);
        }

        if (j < 11) {
            #pragma unroll
            for (int q = 0; q < 6; ++q) ((u32x4*)wbuf[cb ^ 1])[q * 256 + t] = st[q];
        }

        const int col = 16 * j + rr;
        const float bcl = bl[col], bcr = br[col];
        #pragma unroll
        for (int r = 0; r < 4; ++r) {
            size_t o = (size_t)(n0 + kg * 4 + r) * DD + col;
            xlh[o]    = (__fp16)(aL[r] + bcl);
            xr_out[o] = aR[r] + bcr;
        }
        __syncthreads();
    }
}

// ---------------------------------------------------------------------------
// scan_csr: each block locally scans bsum (nb<=256) then its 256-node chunk.
// Replaces scan2+scan3 (one less serialized launch).
// ---------------------------------------------------------------------------
__global__ __launch_bounds__(256) void scan_csr(
    const int* __restrict__ deg, const int* __restrict__ bsum,
    int* __restrict__ rowptr, int N, int nb)
{
    __shared__ int sb[256];
    __shared__ int s[256];
    const int t = threadIdx.x;

    int bv = (t < nb) ? bsum[t] : 0;
    sb[t] = bv;
    __syncthreads();
    for (int o = 1; o < 256; o <<= 1) {
        int u = (t >= o) ? sb[t - o] : 0;
        __syncthreads();
        sb[t] += u;
        __syncthreads();
    }
    int blockoff = (blockIdx.x == 0) ? 0 : sb[blockIdx.x - 1];

    int i = blockIdx.x * 256 + t;
    int v = (i < N) ? deg[i] : 0;
    s[t] = v;
    __syncthreads();
    for (int o = 1; o < 256; o <<= 1) {
        int u = (t >= o) ? s[t - o] : 0;
        __syncthreads();
        s[t] += u;
        __syncthreads();
    }
    if (i < N) rowptr[i] = blockoff + s[t] - v;
    if (blockIdx.x == 0 && t == 0) rowptr[N] = sb[nb - 1];
}

__global__ __launch_bounds__(256) void scatter_kernel(
    const int* __restrict__ ei, const int* __restrict__ rowptr,
    const int* __restrict__ pos, int* __restrict__ col, int E)
{
    int e = blockIdx.x * 256 + threadIdx.x;
    if (e >= E) return;
    col[rowptr[ei[E + e]] + pos[e]] = ei[e];
}

// ---------------------------------------------------------------------------
// Pull aggregation: one wave per dst node, 4 edges/iter (16 lanes each),
// 3-slot rotating software pipeline (~9 row-loads + 2 col-loads in flight).
// fp16 packed math: pk_add + sign-mask + fdot2 (lrelu+log2e folded), RED8,
// exp2, mixed-precision fma accumulate. 128-thread blocks (2 nodes).
// ---------------------------------------------------------------------------
__global__ __launch_bounds__(128) void agg_kernel(
    const __fp16* __restrict__ xlh, const float* __restrict__ att,
    const float* __restrict__ x, const float* __restrict__ bias,
    const int* __restrict__ rowptr, const int* __restrict__ col,
    float* __restrict__ out, int N)
{
    const int node = blockIdx.x * 2 + (threadIdx.x >> 6);
    if (node >= N) return;
    const int lane = threadIdx.x & 63;
    const int l16  = lane & 15;
    const int q    = lane >> 4;          // edge slot 0..3
    const float LOG2E = 1.4426950408889634f;

    h2 xrh[3][2], w6[3][2], w4[3][2];
    #pragma unroll
    for (int s = 0; s < 3; ++s) {
        f32x4 xv = *(const f32x4*)(out + (size_t)node * DD + 64 * s + 4 * l16);
        xrh[s][0] = __builtin_amdgcn_cvt_pkrtz(xv[0], xv[1]);
        xrh[s][1] = __builtin_amdgcn_cvt_pkrtz(xv[2], xv[3]);
        f32x4 wv = *(const f32x4*)(att + 64 * s + 4 * l16);
        w6[s][0] = __builtin_amdgcn_cvt_pkrtz(0.6f * LOG2E * wv[0], 0.6f * LOG2E * wv[1]);
        w6[s][1] = __builtin_amdgcn_cvt_pkrtz(0.6f * LOG2E * wv[2], 0.6f * LOG2E * wv[3]);
        w4[s][0] = __builtin_amdgcn_cvt_pkrtz(0.4f * LOG2E * wv[0], 0.4f * LOG2E * wv[1]);
        w4[s][1] = __builtin_amdgcn_cvt_pkrtz(0.4f * LOG2E * wv[2], 0.4f * LOG2E * wv[3]);
    }

    float acc[3][4] = {{0.f,0.f,0.f,0.f},{0.f,0.f,0.f,0.f},{0.f,0.f,0.f,0.f}};
    float den[3] = {0.f, 0.f, 0.f};

    const int kbeg  = rowptr[node];
    const int total = rowptr[node + 1] - kbeg + 1;    // self + deg

    auto srcat = [&](int slot) -> int {
        bool v = slot < total;
        int cidx = kbeg + ((v && slot > 0) ? slot - 1 : 0);
        int cv = col[cidx];
        return (slot == 0 || !v) ? node : cv;
    };
    auto loadrow = [&](int src, uint2& X0, uint2& X1, uint2& X2) {
        const char* p = (const char*)xlh + (size_t)src * 384 + 8 * l16;
        X0 = *(const uint2*)(p);
        X1 = *(const uint2*)(p + 128);
        X2 = *(const uint2*)(p + 256);
    };
    auto compute = [&](uint2 X0, uint2 X1, uint2 X2, bool vc) {
        #pragma unroll
        for (int s = 0; s < 3; ++s) {
            const uint2 cu = (s == 0) ? X0 : (s == 1) ? X1 : X2;
            h2 a0 = as_h2(cu.x), a1 = as_h2(cu.y);
            h2 u0 = a0 + xrh[s][0], u1 = a1 + xrh[s][1];
            h2 b0 = as_h2(as_u(u0) & 0x7FFF7FFFu);   // |u| packed
            h2 b1 = as_h2(as_u(u1) & 0x7FFF7FFFu);
            float p = __builtin_amdgcn_fdot2(u0, w6[s][0], 0.f, false);
            p = __builtin_amdgcn_fdot2(b0, w4[s][0], p, false);
            p = __builtin_amdgcn_fdot2(u1, w6[s][1], p, false);
            p = __builtin_amdgcn_fdot2(b1, w4[s][1], p, false);
            RED8(p);
            p = vc ? p : -1e30f;
            float e = exp2f(p);
            den[s] += e;
            acc[s][0] = fmaf((float)a0.x, e, acc[s][0]);
            acc[s][1] = fmaf((float)a0.y, e, acc[s][1]);
            acc[s][2] = fmaf((float)a1.x, e, acc[s][2]);
            acc[s][3] = fmaf((float)a1.y, e, acc[s][3]);
        }
    };

    uint2 A0, A1, A2, B0, B1, B2, C0, C1, C2;
    {
        int sA = srcat(q), sB = srcat(4 + q), sC = srcat(8 + q);
        loadrow(sA, A0, A1, A2);
        loadrow(sB, B0, B1, B2);
        loadrow(sC, C0, C1, C2);
    }
    int snext = srcat(12 + q);
    int i = 0;
    for (;;) {
        if (i >= total) break;
        compute(A0, A1, A2, (i + q) < total);
        loadrow(snext, A0, A1, A2); snext = srcat(i + 16 + q); i += 4;
        if (i >= total) break;
        compute(B0, B1, B2, (i + q) < total);
        loadrow(snext, B0, B1, B2); snext = srcat(i + 16 + q); i += 4;
        if (i >= total) break;
        compute(C0, C1, C2, (i + q) < total);
        loadrow(snext, C0, C1, C2); snext = srcat(i + 16 + q); i += 4;
    }

    // combine the four edge slots
    #pragma unroll
    for (int s = 0; s < 3; ++s) {
        den[s] += __shfl_xor(den[s], 16); den[s] += __shfl_xor(den[s], 32);
        #pragma unroll
        for (int j = 0; j < 4; ++j) {
            acc[s][j] += __shfl_xor(acc[s][j], 16);
            acc[s][j] += __shfl_xor(acc[s][j], 32);
        }
    }

    if (q == 0) {
        #pragma unroll
        for (int s = 0; s < 3; ++s) {
            float inv = __builtin_amdgcn_rcpf(den[s] + 1e-16f);
            f32x4 xv = *(const f32x4*)(x + (size_t)node * DD + 64 * s + 4 * l16);
            f32x4 bv = *(const f32x4*)(bias + 64 * s + 4 * l16);
            f32x4 o;
            #pragma unroll
            for (int j = 0; j < 4; ++j) {
                float v = fmaf(acc[s][j], inv, xv[j] + bv[j]);
                o[j] = v > 0.f ? v : 0.f;
            }
            *(f32x4*)(out + (size_t)node * DD + 64 * s + 4 * l16) = o;
        }
    }
}

extern "C" void kernel_launch(void* const* d_in, const int* in_sizes, int n_in,
                              void* d_out, int out_size, void* d_ws, size_t ws_size,
                              hipStream_t stream)
{
    const float* x    = (const float*)d_in[0];
    const float* Wl   = (const float*)d_in[1];
    const float* bl   = (const float*)d_in[2];
    const float* Wr   = (const float*)d_in[3];
    const float* br   = (const float*)d_in[4];
    const float* att  = (const float*)d_in[5];
    const float* bias = (const float*)d_in[6];
    const int*   ei   = (const int*)d_in[7];

    const int N = in_sizes[0] / DD;     // 50000
    const int E = in_sizes[7] / 2;      // 800000
    const int nb    = ceil_div(N, 256); // 196 scan blocks
    const int convB = ceil_div(DD * DD, 256);
    const int degB  = ceil_div(E, 256);
    const int projB = ceil_div(N, 64);

    float* out = (float*)d_out;
    char*  ws  = (char*)d_ws;

    size_t off = 0;
    __fp16* xlh = (__fp16*)(ws + off); off = alignup(off + (size_t)N * DD * 2);
    unsigned short* wcomb = (unsigned short*)(ws + off); off = alignup(off + (size_t)12 * 12288 * 2);
    int* rowptr = (int*)(ws + off); off = alignup(off + (size_t)(N + 1) * 4);
    int* deg    = (int*)(ws + off); off = alignup(off + (size_t)N * 4);
    int* pos    = (int*)(ws + off); off = alignup(off + (size_t)E * 4);
    int* bsum   = (int*)(ws + off); off = alignup(off + 256 * 4);
    int* col    = (int*)(ws + off); off = alignup(off + (size_t)E * 4 + 256);

    hipMemsetAsync(deg, 0, (size_t)N * sizeof(int), stream);

    k1_convw_deg<<<convB + degB, 256, 0, stream>>>(Wl, Wr, wcomb, ei, deg, pos, E, convB);
    k2_proj_scan1<<<projB + nb, 256, 0, stream>>>(x, wcomb, bl, br, xlh, out, N, deg, bsum, projB);
    scan_csr<<<nb, 256, 0, stream>>>(deg, bsum, rowptr, N, nb);
    scatter_kernel<<<degB, 256, 0, stream>>>(ei, rowptr, pos, col, E);
    agg_kernel<<<ceil_div(N, 2), 128, 0, stream>>>(xlh, att, x, bias, rowptr, col, out, N);
}